// Round 6
// baseline (1014.420 us; speedup 1.0000x reference)
//
#include <hip/hip_runtime.h>
#include <hip/hip_fp16.h>
#include <cstdint>
#include <cstddef>

#define NN 100000
#define NE 1600000
#define NEP (NE + NN)          // 1,700,000
#define NBUCK ((NN + 63) / 64) // 1563 buckets of 64 dst nodes

typedef __attribute__((ext_vector_type(8))) _Float16 half8;
typedef __attribute__((ext_vector_type(4))) float float4v;

__device__ __forceinline__ float elu_f(float x) {
    return x > 0.f ? x : __expf(x) - 1.f;
}

// DPP row_ror add; full 16-lane-row sum, result in all lanes of the row
template<int N>
__device__ __forceinline__ float rrot_add(float x) {
    int s = __builtin_amdgcn_update_dpp(0, __float_as_int(x), 0x120 | N, 0xF, 0xF, true);
    return x + __int_as_float(s);
}
__device__ __forceinline__ float row16_allsum(float x) {
    x = rrot_add<1>(x); x = rrot_add<2>(x); x = rrot_add<4>(x); x = rrot_add<8>(x);
    return x;
}

// ================= CSR build: bucketed counting sort =================

__global__ __launch_bounds__(256) void bucket_hist(const int* __restrict__ ei, int* __restrict__ bcount)
{
    int e = blockIdx.x * 256 + threadIdx.x;
    if (e >= NEP) return;
    int dst = (e < NE) ? ei[NE + e] : e - NE;
    atomicAdd(&bcount[dst >> 6], 1);
}

__global__ __launch_bounds__(256) void bucket_scan(const int* __restrict__ bcount,
                                                   int* __restrict__ bbase, int* __restrict__ bcursor,
                                                   int* __restrict__ off)
{
    __shared__ int wt[4];
    const int CH = 7;               // 256*7 >= NBUCK
    int t = threadIdx.x;
    int st = t * CH;
    int loc[CH]; int s = 0;
    #pragma unroll
    for (int i = 0; i < CH; i++) {
        int j = st + i;
        int v = (j < NBUCK) ? bcount[j] : 0;
        loc[i] = s; s += v;
    }
    int lane = t & 63, w = t >> 6;
    int x = s;
    for (int d = 1; d < 64; d <<= 1) { int y = __shfl_up(x, d, 64); if (lane >= d) x += y; }
    if (lane == 63) wt[w] = x;
    __syncthreads();
    int wb = 0;
    for (int i = 0; i < w; i++) wb += wt[i];
    int base = wb + x - s;          // exclusive prefix for this thread's chunk
    #pragma unroll
    for (int i = 0; i < CH; i++) {
        int j = st + i;
        if (j < NBUCK) { int b = base + loc[i]; bbase[j] = b; bcursor[j] = b; }
    }
    if (t == 255) { bbase[NBUCK] = base + s; off[NN] = NEP; }
}

__global__ __launch_bounds__(256) void bucket_scatter(const int* __restrict__ ei,
                                                      int* __restrict__ bcursor, int2* __restrict__ ebuf)
{
    int e = blockIdx.x * 256 + threadIdx.x;
    if (e >= NEP) return;
    int src, dst;
    if (e < NE) { src = ei[e]; dst = ei[NE + e]; } else { src = dst = e - NE; }
    int pos = atomicAdd(&bcursor[dst >> 6], 1);
    ebuf[pos] = make_int2(src, dst);
}

// one block per bucket: LDS counting sort; writes off[] and csr[]
__global__ __launch_bounds__(256) void bucket_csr(const int* __restrict__ bbase,
                                                  const int2* __restrict__ ebuf,
                                                  int* __restrict__ off, int* __restrict__ csr)
{
    __shared__ int cnt[64];
    __shared__ int cur[64];
    int b = blockIdx.x;
    int d0 = b << 6;
    int e0 = bbase[b], e1 = bbase[b + 1];
    int tid = threadIdx.x;
    if (tid < 64) cnt[tid] = 0;
    __syncthreads();
    for (int i = e0 + tid; i < e1; i += 256) {
        int2 ed = ebuf[i];
        atomicAdd(&cnt[ed.y - d0], 1);
    }
    __syncthreads();
    if (tid < 64) {
        int c = cnt[tid];
        int x = c;
        for (int d = 1; d < 64; d <<= 1) { int y = __shfl_up(x, d, 64); if (tid >= d) x += y; }
        int excl = x - c;
        int node = d0 + tid;
        if (node < NN) off[node] = e0 + excl;
        cur[tid] = e0 + excl;
    }
    __syncthreads();
    for (int i = e0 + tid; i < e1; i += 256) {
        int2 ed = ebuf[i];
        int p = atomicAdd(&cur[ed.y - d0], 1);
        csr[p] = ed.x;
    }
}

// ================= node feature prep (fp16 x, stride 96, pre-zeroed pad) =================

__global__ __launch_bounds__(256) void bio_kernel(
    const float* __restrict__ xb, const float* __restrict__ W1, const float* __restrict__ b1,
    const float* __restrict__ g0, const float* __restrict__ bb0,
    const float* __restrict__ m0, const float* __restrict__ v0,
    const float* __restrict__ W2, const float* __restrict__ b2,
    __half* __restrict__ xh)
{
    __shared__ float sW1[16*64], sW2[16*16], sb1[16], sb2[16], ss[16], st[16];
    int tid = threadIdx.x;
    for (int idx = tid; idx < 1024; idx += 256) sW1[idx] = W1[idx];
    if (tid < 256) sW2[tid] = W2[tid];
    if (tid < 16) {
        sb1[tid] = b1[tid]; sb2[tid] = b2[tid];
        float s = g0[tid] * rsqrtf(v0[tid] + 1e-5f);
        ss[tid] = s; st[tid] = bb0[tid] - m0[tid] * s;
    }
    __syncthreads();
    int i = blockIdx.x * 256 + tid;
    if (i >= NN) return;
    float bio[64];
    const float4* p = (const float4*)(xb + (size_t)i * 64);
    #pragma unroll
    for (int q = 0; q < 16; q++) {
        float4 f = p[q];
        bio[q*4] = f.x; bio[q*4+1] = f.y; bio[q*4+2] = f.z; bio[q*4+3] = f.w;
    }
    float t1[16];
    #pragma unroll
    for (int j = 0; j < 16; j++) {
        float acc = sb1[j];
        #pragma unroll
        for (int k = 0; k < 64; k++) acc += bio[k] * sW1[j*64 + k];
        acc = acc * ss[j] + st[j];
        t1[j] = elu_f(acc);
    }
    __half* xo = xh + (size_t)i * 96 + 50;
    #pragma unroll
    for (int j = 0; j < 16; j++) {
        float acc = sb2[j];
        #pragma unroll
        for (int k = 0; k < 16; k++) acc += t1[k] * sW2[j*16 + k];
        xo[j] = __float2half(elu_f(acc));
    }
}

__global__ __launch_bounds__(256) void copy_pca(const float* __restrict__ xp, __half* __restrict__ xh)
{
    int t = blockIdx.x * 256 + threadIdx.x;
    if (t >= NN * 50) return;
    int i = t / 50, j = t - i * 50;
    xh[(size_t)i * 96 + j] = __float2half(xp[t]);
}

// ================= weight conversion =================

// Wl(NH x K) || Wr(NH x K) -> wcat fp16 [2*NH][KPAD] (zero-padded K), bcat fp32 [2*NH]
__global__ __launch_bounds__(256) void wconvert(
    const float* __restrict__ Wl, const float* __restrict__ Wr,
    const float* __restrict__ bl, const float* __restrict__ br,
    __half* __restrict__ wcat, float* __restrict__ bcat,
    int NH, int K, int KPAD)
{
    int total = 2 * NH * KPAD;
    for (int t = blockIdx.x * 256 + threadIdx.x; t < total; t += gridDim.x * 256) {
        int j = t / KPAD, k = t - j * KPAD;
        float v = 0.f;
        if (k < K) v = (j < NH) ? Wl[j * K + k] : Wr[(j - NH) * K + k];
        wcat[t] = __float2half(v);
    }
    int t = blockIdx.x * 256 + threadIdx.x;
    if (t < 2 * NH) bcat[t] = (t < NH) ? bl[t] : br[t - NH];
}

// ================= MFMA f16 GEMM: out[n][NC] = in[n][K] @ wcat[NC][K]^T + bcat =================
// K = KT*32. Block: 256 thr = 4 waves, 64 rows. fp16 out.
template<int KT, int NC>
__global__ __launch_bounds__(256) void mfma_gemm(
    const __half* __restrict__ in, const __half* __restrict__ wcat,
    const float* __restrict__ bcat, __half* __restrict__ outh, int n)
{
    constexpr int K = KT * 32;
    constexpr int KP = K + 8;          // LDS stride in halves (multiple of 8, odd*8 -> conflict-free-ish)
    __shared__ __half sW[NC * KP];
    __shared__ __half sX[64 * KP];
    __shared__ float sB[NC];
    int tid = threadIdx.x;
    for (int idx = tid * 8; idx < NC * K; idx += 256 * 8) {
        int r = idx / K, c = idx - r * K;
        *(half8*)(&sW[r * KP + c]) = *(const half8*)(&wcat[r * K + c]);
    }
    for (int idx = tid; idx < NC; idx += 256) sB[idx] = bcat[idx];
    int row0 = blockIdx.x * 64;
    half8 hz = {0, 0, 0, 0, 0, 0, 0, 0};
    for (int idx = tid * 8; idx < 64 * K; idx += 256 * 8) {
        int r = idx / K, c = idx - r * K;
        int gr = row0 + r;
        half8 v = (gr < n) ? *(const half8*)(&in[(size_t)gr * K + c]) : hz;
        *(half8*)(&sX[r * KP + c]) = v;
    }
    __syncthreads();
    int w = tid >> 6, lane = tid & 63;
    int m = lane & 15, quad = lane >> 4;
    half8 a[KT];
    #pragma unroll
    for (int kt = 0; kt < KT; kt++)
        a[kt] = *(const half8*)(&sX[(w * 16 + m) * KP + kt * 32 + quad * 8]);
    #pragma unroll 1
    for (int nt = 0; nt < NC / 16; nt++) {
        float4v acc = {0.f, 0.f, 0.f, 0.f};
        #pragma unroll
        for (int kt = 0; kt < KT; kt++) {
            half8 bfrag = *(const half8*)(&sW[(nt * 16 + m) * KP + kt * 32 + quad * 8]);
            acc = __builtin_amdgcn_mfma_f32_16x16x32_f16(a[kt], bfrag, acc, 0, 0, 0);
        }
        int col = nt * 16 + m;
        float bias = sB[col];
        #pragma unroll
        for (int i = 0; i < 4; i++) {
            int r = row0 + w * 16 + quad * 4 + i;
            if (r < n) outh[(size_t)r * NC + col] = __float2half(acc[i] + bias);
        }
    }
}

// ================= fused GATv2 layer 1: one wave per dst node =================
// xcat [N][256] fp16: cols 0..127 = xl, 128..255 = xr. h1 out fp16 [N][128].
__global__ __launch_bounds__(256) void fused_gat1(
    const int* __restrict__ off, const int* __restrict__ csr,
    const __half2* __restrict__ xcat, const float* __restrict__ att,
    const float* __restrict__ bias, const float* __restrict__ g,
    const float* __restrict__ b, const float* __restrict__ m,
    const float* __restrict__ v, __half2* __restrict__ h1)
{
    int wave = threadIdx.x >> 6;
    int lane = threadIdx.x & 63;
    int node = blockIdx.x * 4 + wave;
    if (node >= NN) return;
    int ch = lane * 2;

    float2 xrv = __half22float2(xcat[(size_t)node * 128 + 64 + lane]);
    float2 av  = *(const float2*)(att + ch);

    int k0 = off[node], k1 = off[node + 1];
    float accx = 0.f, accy = 0.f, denom = 0.f;

    for (int base = k0; base < k1; base += 64) {
        int nb = min(64, k1 - base);
        int mysrc = (lane < nb) ? csr[base + lane] : 0;
        int cs = __builtin_amdgcn_readlane(mysrc, 0);
        __half2 hcur = xcat[(size_t)cs * 128 + lane];
        for (int t = 0; t < nb; t++) {
            int tn = (t + 1 < nb) ? t + 1 : t;
            int ns = __builtin_amdgcn_readlane(mysrc, tn);
            __half2 hnxt = xcat[(size_t)ns * 128 + lane];
            float2 xlv = __half22float2(hcur);
            float sx = xlv.x + xrv.x; sx = fmaxf(sx, 0.2f * sx);
            float sy = xlv.y + xrv.y; sy = fmaxf(sy, 0.2f * sy);
            float pp = sx * av.x + sy * av.y;
            pp = row16_allsum(pp);
            float wgt = __expf(pp);
            denom += wgt;
            accx = fmaf(xlv.x, wgt, accx);
            accy = fmaf(xlv.y, wgt, accy);
            hcur = hnxt;
        }
    }
    float inv = 1.f / (denom + 1e-16f);
    float sX = g[ch]     * rsqrtf(v[ch]     + 1e-5f);
    float sY = g[ch + 1] * rsqrtf(v[ch + 1] + 1e-5f);
    float ox = accx * inv + bias[ch];
    float oy = accy * inv + bias[ch + 1];
    ox = ox * sX + (b[ch]     - m[ch]     * sX);
    oy = oy * sY + (b[ch + 1] - m[ch + 1] * sY);
    h1[(size_t)node * 64 + lane] = __floats2half2_rn(elu_f(ox), elu_f(oy));
}

// ================= fused GATv2 layer 2: one wave per dst node =================
// xcat2 [N][64] fp16: cols 0..31 = xl, 32..63 = xr. 4 edges/iter x 16 ch-pairs.
__global__ __launch_bounds__(256) void fused_gat2(
    const int* __restrict__ off, const int* __restrict__ csr,
    const __half2* __restrict__ xcat2, const float* __restrict__ att,
    const float* __restrict__ bias, const float* __restrict__ g,
    const float* __restrict__ b, const float* __restrict__ m,
    const float* __restrict__ v, float* __restrict__ h2)
{
    int wave = threadIdx.x >> 6;
    int lane = threadIdx.x & 63;
    int node = blockIdx.x * 4 + wave;
    if (node >= NN) return;
    int row = lane >> 4;
    int cp  = lane & 15;
    int c   = cp * 2;

    float2 xrv = __half22float2(xcat2[(size_t)node * 32 + 16 + cp]);
    float2 av  = *(const float2*)(att + c);

    int k0 = off[node], k1 = off[node + 1];
    float accx = 0.f, accy = 0.f, denom = 0.f;

    for (int base = k0; base < k1; base += 64) {
        int nb = min(64, k1 - base);
        int mysrc = (lane < nb) ? csr[base + lane] : 0;
        for (int t = 0; t < nb; t += 4) {
            int i1 = min(t + 1, nb - 1), i2 = min(t + 2, nb - 1), i3 = min(t + 3, nb - 1);
            int s0 = __builtin_amdgcn_readlane(mysrc, t);
            int s1 = __builtin_amdgcn_readlane(mysrc, i1);
            int s2 = __builtin_amdgcn_readlane(mysrc, i2);
            int s3 = __builtin_amdgcn_readlane(mysrc, i3);
            int sa  = (row & 1) ? s1 : s0;
            int sb_ = (row & 1) ? s3 : s2;
            int ss  = (row & 2) ? sb_ : sa;
            float2 xlv = __half22float2(xcat2[(size_t)ss * 32 + cp]);
            float sx = xlv.x + xrv.x; sx = fmaxf(sx, 0.2f * sx);
            float sy = xlv.y + xrv.y; sy = fmaxf(sy, 0.2f * sy);
            float pp = sx * av.x + sy * av.y;
            pp = row16_allsum(pp);
            bool valid = (t + row) < nb;
            float wgt = valid ? __expf(pp) : 0.f;
            denom += wgt;
            accx = fmaf(xlv.x, wgt, accx);
            accy = fmaf(xlv.y, wgt, accy);
        }
    }
    accx  += __shfl_xor(accx, 16, 64);  accx  += __shfl_xor(accx, 32, 64);
    accy  += __shfl_xor(accy, 16, 64);  accy  += __shfl_xor(accy, 32, 64);
    denom += __shfl_xor(denom, 16, 64); denom += __shfl_xor(denom, 32, 64);
    if (row == 0) {
        float inv = 1.f / (denom + 1e-16f);
        float sC0 = g[c]     * rsqrtf(v[c]     + 1e-5f);
        float sC1 = g[c + 1] * rsqrtf(v[c + 1] + 1e-5f);
        float o0 = accx * inv + bias[c];
        float o1 = accy * inv + bias[c + 1];
        o0 = o0 * sC0 + (b[c]     - m[c]     * sC0);
        o1 = o1 * sC1 + (b[c + 1] - m[c + 1] * sC1);
        float2 o; o.x = elu_f(o0); o.y = elu_f(o1);
        *(float2*)(h2 + (size_t)node * 32 + c) = o;
    }
}

// ================= prediction head: Linear(32,50) =================

__global__ __launch_bounds__(256) void predk(
    const float* __restrict__ h, const float* __restrict__ W,
    const float* __restrict__ bias, float* __restrict__ out)
{
    __shared__ float sW[50 * 32];
    __shared__ float sb[50];
    int tid = threadIdx.x;
    for (int idx = tid; idx < 1600; idx += 256) sW[idx] = W[idx];
    if (tid < 50) sb[tid] = bias[tid];
    __syncthreads();
    int t = blockIdx.x * 256 + tid;
    if (t >= NN * 50) return;
    int i = t / 50, j = t - i * 50;
    const float* hr = h + (size_t)i * 32;
    float acc = sb[j];
    #pragma unroll
    for (int k = 0; k < 32; k++) acc += hr[k] * sW[j * 32 + k];
    out[t] = acc;
}

extern "C" void kernel_launch(void* const* d_in, const int* in_sizes, int n_in,
                              void* d_out, int out_size, void* d_ws, size_t ws_size,
                              hipStream_t stream)
{
    const float* x_pca = (const float*)d_in[0];
    const float* x_bio = (const float*)d_in[1];
    const int*   ei    = (const int*)d_in[2];
    const float* bioW1 = (const float*)d_in[3];
    const float* biob1 = (const float*)d_in[4];
    const float* bn0_g = (const float*)d_in[5];
    const float* bn0_b = (const float*)d_in[6];
    const float* bn0_m = (const float*)d_in[7];
    const float* bn0_v = (const float*)d_in[8];
    const float* bioW2 = (const float*)d_in[9];
    const float* biob2 = (const float*)d_in[10];
    const float* Wl1   = (const float*)d_in[11];
    const float* bl1   = (const float*)d_in[12];
    const float* Wr1   = (const float*)d_in[13];
    const float* br1   = (const float*)d_in[14];
    const float* att1  = (const float*)d_in[15];
    const float* bias1 = (const float*)d_in[16];
    const float* bn1_g = (const float*)d_in[17];
    const float* bn1_b = (const float*)d_in[18];
    const float* bn1_m = (const float*)d_in[19];
    const float* bn1_v = (const float*)d_in[20];
    const float* Wl2   = (const float*)d_in[21];
    const float* bl2   = (const float*)d_in[22];
    const float* Wr2   = (const float*)d_in[23];
    const float* br2   = (const float*)d_in[24];
    const float* att2  = (const float*)d_in[25];
    const float* bias2 = (const float*)d_in[26];
    const float* bn2_g = (const float*)d_in[27];
    const float* bn2_b = (const float*)d_in[28];
    const float* bn2_m = (const float*)d_in[29];
    const float* bn2_v = (const float*)d_in[30];
    const float* predW = (const float*)d_in[31];
    const float* predb = (const float*)d_in[32];

    float* ws = (float*)d_ws;
    __half* xh    = (__half*)ws;                       // N*96 halves  (4.8M floats)
    float*  p0    = ws + 4800000;
    __half* xcat1 = (__half*)p0;                       // N*256 halves (12.8M floats)
    float*  p1    = p0 + 12800000;
    __half* h1h   = (__half*)p1;                       // N*128 halves (6.4M floats)
    float*  p2    = p1 + 6400000;
    __half* xcat2 = (__half*)p2;                       // N*64 halves  (3.2M floats)
    float*  p3    = p2 + 3200000;
    float*  h2    = p3;                                // N*32 floats
    float*  p4    = p3 + 3200000;
    __half* wcat1 = (__half*)p4;                       // 256*96 halves (12288 floats)
    float*  bcat1 = p4 + 12288;                        // 256
    __half* wcat2 = (__half*)(bcat1 + 256);            // 64*128 halves (4096 floats)
    float*  bcat2 = bcat1 + 256 + 4096;                // 64
    int2*   ebuf  = (int2*)(bcat2 + 64);               // NEP int2 (8B-aligned: offset even)
    int*    ib    = (int*)(ebuf + NEP);
    int*    bcount  = ib;                              // NBUCK
    int*    bbase   = bcount + NBUCK;                  // NBUCK+1
    int*    bcursor = bbase + NBUCK + 1;               // NBUCK
    int*    off     = bcursor + NBUCK;                 // NN+1
    int*    csr     = off + NN + 1;                    // NEP

    float* out = (float*)d_out;

    // ---- zero-init: x pad region + bucket counts ----
    hipMemsetAsync(xh, 0, (size_t)NN * 96 * sizeof(__half), stream);
    hipMemsetAsync(bcount, 0, (size_t)NBUCK * sizeof(int), stream);

    // ---- CSR build (bucketed counting sort) ----
    bucket_hist<<<(NEP + 255) / 256, 256, 0, stream>>>(ei, bcount);
    bucket_scan<<<1, 256, 0, stream>>>(bcount, bbase, bcursor, off);
    bucket_scatter<<<(NEP + 255) / 256, 256, 0, stream>>>(ei, bcursor, ebuf);
    bucket_csr<<<NBUCK, 256, 0, stream>>>(bbase, ebuf, off, csr);

    // ---- node features (fp16) ----
    bio_kernel<<<(NN + 255) / 256, 256, 0, stream>>>(
        x_bio, bioW1, biob1, bn0_g, bn0_b, bn0_m, bn0_v, bioW2, biob2, xh);
    copy_pca<<<(NN * 50 + 255) / 256, 256, 0, stream>>>(x_pca, xh);

    // ---- weight conversion ----
    wconvert<<<96, 256, 0, stream>>>(Wl1, Wr1, bl1, br1, wcat1, bcat1, 128, 66, 96);
    wconvert<<<32, 256, 0, stream>>>(Wl2, Wr2, bl2, br2, wcat2, bcat2, 32, 128, 128);

    // ---- layer-1 transform: [N][96] @ [256][96]^T -> xcat1 ----
    mfma_gemm<3, 256><<<(NN + 63) / 64, 256, 0, stream>>>(xh, wcat1, bcat1, xcat1, NN);

    // ---- fused layer-1 edge phase + bias/BN/ELU -> h1h fp16 ----
    fused_gat1<<<(NN + 3) / 4, 256, 0, stream>>>(
        off, csr, (const __half2*)xcat1, att1, bias1, bn1_g, bn1_b, bn1_m, bn1_v, (__half2*)h1h);

    // ---- layer-2 transform: [N][128] @ [64][128]^T -> xcat2 ----
    mfma_gemm<4, 64><<<(NN + 63) / 64, 256, 0, stream>>>(h1h, wcat2, bcat2, xcat2, NN);

    // ---- fused layer-2 edge phase + bias/BN/ELU -> h2 fp32 ----
    fused_gat2<<<(NN + 3) / 4, 256, 0, stream>>>(
        off, csr, (const __half2*)xcat2, att2, bias2, bn2_g, bn2_b, bn2_m, bn2_v, h2);

    // ---- prediction head ----
    predk<<<(NN * 50 + 255) / 256, 256, 0, stream>>>(h2, predW, predb, out);
}

// Round 7
// 481.839 us; speedup vs baseline: 2.1053x; 2.1053x over previous
//
#include <hip/hip_runtime.h>
#include <hip/hip_fp16.h>
#include <cstdint>
#include <cstddef>

#define NN 100000
#define NE 1600000
#define NEP (NE + NN)              // 1,700,000
#define NBLK 200                   // partition blocks
#define CHUNK ((NEP + NBLK - 1) / NBLK)   // 8500
#define NBUCK2 ((NN + 255) / 256)  // 391 buckets of 256 dst nodes
#define HISTN (NBUCK2 * NBLK)      // 78,200
#define HSCAN_BLOCKS ((HISTN + 1023) / 1024)  // 77

typedef __attribute__((ext_vector_type(8))) _Float16 half8;
typedef __attribute__((ext_vector_type(4))) float float4v;

__device__ __forceinline__ float elu_f(float x) {
    return x > 0.f ? x : __expf(x) - 1.f;
}

template<int N>
__device__ __forceinline__ float rrot_add(float x) {
    int s = __builtin_amdgcn_update_dpp(0, __float_as_int(x), 0x120 | N, 0xF, 0xF, true);
    return x + __int_as_float(s);
}
__device__ __forceinline__ float row16_allsum(float x) {
    x = rrot_add<1>(x); x = rrot_add<2>(x); x = rrot_add<4>(x); x = rrot_add<8>(x);
    return x;
}

// ================= CSR build: deterministic radix partition =================

// pass A: per-block histogram over buckets; hist[bucket * NBLK + block]
__global__ __launch_bounds__(256) void part_hist(const int* __restrict__ ei, int* __restrict__ hist)
{
    __shared__ int cnt[NBUCK2];
    int tid = threadIdx.x, k = blockIdx.x;
    for (int i = tid; i < NBUCK2; i += 256) cnt[i] = 0;
    __syncthreads();
    int e0 = k * CHUNK, e1 = min(e0 + CHUNK, NEP);
    for (int e = e0 + tid; e < e1; e += 256) {
        int dst = (e < NE) ? ei[NE + e] : e - NE;
        atomicAdd(&cnt[dst >> 8], 1);
    }
    __syncthreads();
    for (int i = tid; i < NBUCK2; i += 256) hist[i * NBLK + k] = cnt[i];
}

// generic hierarchical exclusive scan (3 passes)
__global__ __launch_bounds__(256) void scan_p1(const int* __restrict__ src, int* __restrict__ part, int n)
{
    __shared__ int wsum[4];
    int t = threadIdx.x;
    int i0 = blockIdx.x * 1024 + t * 4;
    int s = 0;
    if (i0 + 3 < n) { int4 d = *(const int4*)(src + i0); s = d.x + d.y + d.z + d.w; }
    else { for (int k = 0; k < 4; k++) if (i0 + k < n) s += src[i0 + k]; }
    for (int d = 1; d < 64; d <<= 1) s += __shfl_xor(s, d, 64);
    if ((t & 63) == 0) wsum[t >> 6] = s;
    __syncthreads();
    if (t == 0) part[blockIdx.x] = wsum[0] + wsum[1] + wsum[2] + wsum[3];
}

__global__ __launch_bounds__(128) void scan_p2(int* __restrict__ part, int nb, int* __restrict__ off)
{
    __shared__ int wt[2];
    int t = threadIdx.x;
    int lane = t & 63, w = t >> 6;
    int v = (t < nb) ? part[t] : 0;
    int x = v;
    for (int d = 1; d < 64; d <<= 1) { int y = __shfl_up(x, d, 64); if (lane >= d) x += y; }
    if (lane == 63) wt[w] = x;
    __syncthreads();
    int base = (w == 1) ? wt[0] : 0;
    int excl = base + x - v;
    if (t < nb) part[t] = excl;
    if (t == 0) off[NN] = NEP;
}

__global__ __launch_bounds__(256) void scan_p3(int* __restrict__ data, const int* __restrict__ part, int n)
{
    __shared__ int wsum[4];
    int t = threadIdx.x, lane = t & 63, w = t >> 6;
    int i0 = blockIdx.x * 1024 + t * 4;
    int d0 = 0, d1 = 0, d2 = 0, d3 = 0;
    if (i0 + 3 < n) { int4 d = *(const int4*)(data + i0); d0 = d.x; d1 = d.y; d2 = d.z; d3 = d.w; }
    else if (i0 < n) {
        d0 = data[i0];
        if (i0 + 1 < n) d1 = data[i0 + 1];
        if (i0 + 2 < n) d2 = data[i0 + 2];
    }
    int s = d0 + d1 + d2 + d3;
    int x = s;
    for (int d = 1; d < 64; d <<= 1) { int y = __shfl_up(x, d, 64); if (lane >= d) x += y; }
    if (lane == 63) wsum[w] = x;
    __syncthreads();
    int wb = 0;
    for (int i = 0; i < w; i++) wb += wsum[i];
    int base = part[blockIdx.x] + wb + x - s;
    if (i0 < n)     data[i0]     = base;
    if (i0 + 1 < n) data[i0 + 1] = base + d0;
    if (i0 + 2 < n) data[i0 + 2] = base + d0 + d1;
    if (i0 + 3 < n) data[i0 + 3] = base + d0 + d1 + d2;
}

// pass C: scatter packed (src | dst_local<<24) into per-(block,bucket) runs; LDS cursors only
__global__ __launch_bounds__(256) void part_scatter(const int* __restrict__ ei,
                                                    const int* __restrict__ hist,
                                                    unsigned* __restrict__ ebuf)
{
    __shared__ int cur[NBUCK2];
    int tid = threadIdx.x, k = blockIdx.x;
    for (int i = tid; i < NBUCK2; i += 256) cur[i] = hist[i * NBLK + k];
    __syncthreads();
    int e0 = k * CHUNK, e1 = min(e0 + CHUNK, NEP);
    for (int e = e0 + tid; e < e1; e += 256) {
        int src, dst;
        if (e < NE) { src = ei[e]; dst = ei[NE + e]; } else { src = dst = e - NE; }
        int pos = atomicAdd(&cur[dst >> 8], 1);
        ebuf[pos] = (unsigned)src | ((unsigned)(dst & 255) << 24);
    }
}

// one block per 256-node bucket: LDS counting sort -> off[], csr[]
__global__ __launch_bounds__(256) void bucket_csr(const int* __restrict__ hist,
                                                  const unsigned* __restrict__ ebuf,
                                                  int* __restrict__ off, int* __restrict__ csr)
{
    __shared__ int cnt[256];
    __shared__ int cur[256];
    __shared__ int wsum[4];
    int b = blockIdx.x;
    int d0 = b << 8;
    int tid = threadIdx.x;
    int e0 = hist[b * NBLK];
    int e1 = (b + 1 < NBUCK2) ? hist[(b + 1) * NBLK] : NEP;
    cnt[tid] = 0;
    __syncthreads();
    for (int i = e0 + tid; i < e1; i += 256) atomicAdd(&cnt[ebuf[i] >> 24], 1);
    __syncthreads();
    int c = cnt[tid];
    int x = c;
    int lane = tid & 63, w = tid >> 6;
    for (int d = 1; d < 64; d <<= 1) { int y = __shfl_up(x, d, 64); if (lane >= d) x += y; }
    if (lane == 63) wsum[w] = x;
    __syncthreads();
    int wb = 0;
    for (int i = 0; i < w; i++) wb += wsum[i];
    int excl = wb + x - c;
    cur[tid] = e0 + excl;
    int node = d0 + tid;
    if (node < NN) off[node] = e0 + excl;
    __syncthreads();
    for (int i = e0 + tid; i < e1; i += 256) {
        unsigned v = ebuf[i];
        int p = atomicAdd(&cur[v >> 24], 1);
        csr[p] = (int)(v & 0xFFFFFF);
    }
}

// ================= node feature prep (fp16 x, stride 96; writes own pad) =================

__global__ __launch_bounds__(256) void bio_kernel(
    const float* __restrict__ xb, const float* __restrict__ W1, const float* __restrict__ b1,
    const float* __restrict__ g0, const float* __restrict__ bb0,
    const float* __restrict__ m0, const float* __restrict__ v0,
    const float* __restrict__ W2, const float* __restrict__ b2,
    __half* __restrict__ xh)
{
    __shared__ float sW1[16*64], sW2[16*16], sb1[16], sb2[16], ss[16], st[16];
    int tid = threadIdx.x;
    for (int idx = tid; idx < 1024; idx += 256) sW1[idx] = W1[idx];
    if (tid < 256) sW2[tid] = W2[tid];
    if (tid < 16) {
        sb1[tid] = b1[tid]; sb2[tid] = b2[tid];
        float s = g0[tid] * rsqrtf(v0[tid] + 1e-5f);
        ss[tid] = s; st[tid] = bb0[tid] - m0[tid] * s;
    }
    __syncthreads();
    int i = blockIdx.x * 256 + tid;
    if (i >= NN) return;
    float bio[64];
    const float4* p = (const float4*)(xb + (size_t)i * 64);
    #pragma unroll
    for (int q = 0; q < 16; q++) {
        float4 f = p[q];
        bio[q*4] = f.x; bio[q*4+1] = f.y; bio[q*4+2] = f.z; bio[q*4+3] = f.w;
    }
    float t1[16];
    #pragma unroll
    for (int j = 0; j < 16; j++) {
        float acc = sb1[j];
        #pragma unroll
        for (int k = 0; k < 64; k++) acc += bio[k] * sW1[j*64 + k];
        acc = acc * ss[j] + st[j];
        t1[j] = elu_f(acc);
    }
    __half* xo = xh + (size_t)i * 96 + 50;
    #pragma unroll
    for (int j = 0; j < 16; j++) {
        float acc = sb2[j];
        #pragma unroll
        for (int k = 0; k < 16; k++) acc += t1[k] * sW2[j*16 + k];
        xo[j] = __float2half(elu_f(acc));
    }
    // zero pad cols 66..95
    __half2 z2 = __floats2half2_rn(0.f, 0.f);
    __half2* pz = (__half2*)(xh + (size_t)i * 96 + 66);
    #pragma unroll
    for (int j = 0; j < 15; j++) pz[j] = z2;
}

__global__ __launch_bounds__(256) void copy_pca(const float* __restrict__ xp, __half* __restrict__ xh)
{
    int t = blockIdx.x * 256 + threadIdx.x;
    if (t >= NN * 50) return;
    int i = t / 50, j = t - i * 50;
    xh[(size_t)i * 96 + j] = __float2half(xp[t]);
}

// ================= weight conversion =================

__global__ __launch_bounds__(256) void wconvert(
    const float* __restrict__ Wl, const float* __restrict__ Wr,
    const float* __restrict__ bl, const float* __restrict__ br,
    __half* __restrict__ wcat, float* __restrict__ bcat,
    int NH, int K, int KPAD)
{
    int total = 2 * NH * KPAD;
    for (int t = blockIdx.x * 256 + threadIdx.x; t < total; t += gridDim.x * 256) {
        int j = t / KPAD, k = t - j * KPAD;
        float v = 0.f;
        if (k < K) v = (j < NH) ? Wl[j * K + k] : Wr[(j - NH) * K + k];
        wcat[t] = __float2half(v);
    }
    int t = blockIdx.x * 256 + threadIdx.x;
    if (t < 2 * NH) bcat[t] = (t < NH) ? bl[t] : br[t - NH];
}

// predW(50x32) -> wp fp16 [64][32] zero-padded, bp[64]
__global__ __launch_bounds__(256) void wpred_conv(
    const float* __restrict__ W, const float* __restrict__ bias,
    __half* __restrict__ wp, float* __restrict__ bp)
{
    int t = blockIdx.x * 256 + threadIdx.x;
    if (t < 64 * 32) {
        int j = t >> 5;
        wp[t] = __float2half(j < 50 ? W[t - ((j - 50 >= 0) ? 0 : 0)] : 0.f);
        // (j<50: index j*32+k == t)
        if (j < 50) wp[t] = __float2half(W[t]); else wp[t] = __float2half(0.f);
    }
    if (t < 64) bp[t] = (t < 50) ? bias[t] : 0.f;
}

// ================= MFMA f16 GEMM =================
// out[n][NC] = in[n][K] @ wcat[NC][K]^T + bcat.  K = KT*32.  4 waves, 64 rows/block.
// FOUT: write fp32 to out[r*ncol+col] for col<ncol; else fp16 [n][NC].
template<int KT, int NC, bool FOUT>
__global__ __launch_bounds__(256) void mfma_gemm(
    const __half* __restrict__ in, const __half* __restrict__ wcat,
    const float* __restrict__ bcat, void* __restrict__ outv, int n, int ncol)
{
    constexpr int K = KT * 32;
    constexpr int KP = K + 8;
    __shared__ __half sW[NC * KP];
    __shared__ __half sX[64 * KP];
    __shared__ float sB[NC];
    int tid = threadIdx.x;
    for (int idx = tid * 8; idx < NC * K; idx += 256 * 8) {
        int r = idx / K, c = idx - r * K;
        *(half8*)(&sW[r * KP + c]) = *(const half8*)(&wcat[r * K + c]);
    }
    for (int idx = tid; idx < NC; idx += 256) sB[idx] = bcat[idx];
    int row0 = blockIdx.x * 64;
    half8 hz = {0, 0, 0, 0, 0, 0, 0, 0};
    for (int idx = tid * 8; idx < 64 * K; idx += 256 * 8) {
        int r = idx / K, c = idx - r * K;
        int gr = row0 + r;
        half8 v = (gr < n) ? *(const half8*)(&in[(size_t)gr * K + c]) : hz;
        *(half8*)(&sX[r * KP + c]) = v;
    }
    __syncthreads();
    int w = tid >> 6, lane = tid & 63;
    int m = lane & 15, quad = lane >> 4;
    half8 a[KT];
    #pragma unroll
    for (int kt = 0; kt < KT; kt++)
        a[kt] = *(const half8*)(&sX[(w * 16 + m) * KP + kt * 32 + quad * 8]);
    #pragma unroll 1
    for (int nt = 0; nt < NC / 16; nt++) {
        float4v acc = {0.f, 0.f, 0.f, 0.f};
        #pragma unroll
        for (int kt = 0; kt < KT; kt++) {
            half8 bfrag = *(const half8*)(&sW[(nt * 16 + m) * KP + kt * 32 + quad * 8]);
            acc = __builtin_amdgcn_mfma_f32_16x16x32_f16(a[kt], bfrag, acc, 0, 0, 0);
        }
        int col = nt * 16 + m;
        float bias = sB[col];
        #pragma unroll
        for (int i = 0; i < 4; i++) {
            int r = row0 + w * 16 + quad * 4 + i;
            if (r < n) {
                if (FOUT) { if (col < ncol) ((float*)outv)[(size_t)r * ncol + col] = acc[i] + bias; }
                else ((__half*)outv)[(size_t)r * NC + col] = __float2half(acc[i] + bias);
            }
        }
    }
}

// ================= fused GATv2 layer 1 =================
__global__ __launch_bounds__(256) void fused_gat1(
    const int* __restrict__ off, const int* __restrict__ csr,
    const __half2* __restrict__ xcat, const float* __restrict__ att,
    const float* __restrict__ bias, const float* __restrict__ g,
    const float* __restrict__ b, const float* __restrict__ m,
    const float* __restrict__ v, __half2* __restrict__ h1)
{
    int wave = threadIdx.x >> 6;
    int lane = threadIdx.x & 63;
    int node = blockIdx.x * 4 + wave;
    if (node >= NN) return;
    int ch = lane * 2;

    float2 xrv = __half22float2(xcat[(size_t)node * 128 + 64 + lane]);
    float2 av  = *(const float2*)(att + ch);

    int k0 = off[node], k1 = off[node + 1];
    float accx = 0.f, accy = 0.f, denom = 0.f;

    for (int base = k0; base < k1; base += 64) {
        int nb = min(64, k1 - base);
        int mysrc = (lane < nb) ? csr[base + lane] : 0;
        int cs = __builtin_amdgcn_readlane(mysrc, 0);
        __half2 hcur = xcat[(size_t)cs * 128 + lane];
        for (int t = 0; t < nb; t++) {
            int tn = (t + 1 < nb) ? t + 1 : t;
            int ns = __builtin_amdgcn_readlane(mysrc, tn);
            __half2 hnxt = xcat[(size_t)ns * 128 + lane];
            float2 xlv = __half22float2(hcur);
            float sx = xlv.x + xrv.x; sx = fmaxf(sx, 0.2f * sx);
            float sy = xlv.y + xrv.y; sy = fmaxf(sy, 0.2f * sy);
            float pp = sx * av.x + sy * av.y;
            pp = row16_allsum(pp);
            float wgt = __expf(pp);
            denom += wgt;
            accx = fmaf(xlv.x, wgt, accx);
            accy = fmaf(xlv.y, wgt, accy);
            hcur = hnxt;
        }
    }
    float inv = 1.f / (denom + 1e-16f);
    float sX = g[ch]     * rsqrtf(v[ch]     + 1e-5f);
    float sY = g[ch + 1] * rsqrtf(v[ch + 1] + 1e-5f);
    float ox = accx * inv + bias[ch];
    float oy = accy * inv + bias[ch + 1];
    ox = ox * sX + (b[ch]     - m[ch]     * sX);
    oy = oy * sY + (b[ch + 1] - m[ch + 1] * sY);
    h1[(size_t)node * 64 + lane] = __floats2half2_rn(elu_f(ox), elu_f(oy));
}

// ================= fused GATv2 layer 2 (fp16 out) =================
__global__ __launch_bounds__(256) void fused_gat2(
    const int* __restrict__ off, const int* __restrict__ csr,
    const __half2* __restrict__ xcat2, const float* __restrict__ att,
    const float* __restrict__ bias, const float* __restrict__ g,
    const float* __restrict__ b, const float* __restrict__ m,
    const float* __restrict__ v, __half2* __restrict__ h2)
{
    int wave = threadIdx.x >> 6;
    int lane = threadIdx.x & 63;
    int node = blockIdx.x * 4 + wave;
    if (node >= NN) return;
    int row = lane >> 4;
    int cp  = lane & 15;
    int c   = cp * 2;

    float2 xrv = __half22float2(xcat2[(size_t)node * 32 + 16 + cp]);
    float2 av  = *(const float2*)(att + c);

    int k0 = off[node], k1 = off[node + 1];
    float accx = 0.f, accy = 0.f, denom = 0.f;

    for (int base = k0; base < k1; base += 64) {
        int nb = min(64, k1 - base);
        int mysrc = (lane < nb) ? csr[base + lane] : 0;
        for (int t = 0; t < nb; t += 4) {
            int i1 = min(t + 1, nb - 1), i2 = min(t + 2, nb - 1), i3 = min(t + 3, nb - 1);
            int s0 = __builtin_amdgcn_readlane(mysrc, t);
            int s1 = __builtin_amdgcn_readlane(mysrc, i1);
            int s2 = __builtin_amdgcn_readlane(mysrc, i2);
            int s3 = __builtin_amdgcn_readlane(mysrc, i3);
            int sa  = (row & 1) ? s1 : s0;
            int sb_ = (row & 1) ? s3 : s2;
            int ss  = (row & 2) ? sb_ : sa;
            float2 xlv = __half22float2(xcat2[(size_t)ss * 32 + cp]);
            float sx = xlv.x + xrv.x; sx = fmaxf(sx, 0.2f * sx);
            float sy = xlv.y + xrv.y; sy = fmaxf(sy, 0.2f * sy);
            float pp = sx * av.x + sy * av.y;
            pp = row16_allsum(pp);
            bool valid = (t + row) < nb;
            float wgt = valid ? __expf(pp) : 0.f;
            denom += wgt;
            accx = fmaf(xlv.x, wgt, accx);
            accy = fmaf(xlv.y, wgt, accy);
        }
    }
    accx  += __shfl_xor(accx, 16, 64);  accx  += __shfl_xor(accx, 32, 64);
    accy  += __shfl_xor(accy, 16, 64);  accy  += __shfl_xor(accy, 32, 64);
    denom += __shfl_xor(denom, 16, 64); denom += __shfl_xor(denom, 32, 64);
    if (row == 0) {
        float inv = 1.f / (denom + 1e-16f);
        float sC0 = g[c]     * rsqrtf(v[c]     + 1e-5f);
        float sC1 = g[c + 1] * rsqrtf(v[c + 1] + 1e-5f);
        float o0 = accx * inv + bias[c];
        float o1 = accy * inv + bias[c + 1];
        o0 = o0 * sC0 + (b[c]     - m[c]     * sC0);
        o1 = o1 * sC1 + (b[c + 1] - m[c + 1] * sC1);
        h2[(size_t)node * 16 + cp] = __floats2half2_rn(elu_f(o0), elu_f(o1));
    }
}

extern "C" void kernel_launch(void* const* d_in, const int* in_sizes, int n_in,
                              void* d_out, int out_size, void* d_ws, size_t ws_size,
                              hipStream_t stream)
{
    const float* x_pca = (const float*)d_in[0];
    const float* x_bio = (const float*)d_in[1];
    const int*   ei    = (const int*)d_in[2];
    const float* bioW1 = (const float*)d_in[3];
    const float* biob1 = (const float*)d_in[4];
    const float* bn0_g = (const float*)d_in[5];
    const float* bn0_b = (const float*)d_in[6];
    const float* bn0_m = (const float*)d_in[7];
    const float* bn0_v = (const float*)d_in[8];
    const float* bioW2 = (const float*)d_in[9];
    const float* biob2 = (const float*)d_in[10];
    const float* Wl1   = (const float*)d_in[11];
    const float* bl1   = (const float*)d_in[12];
    const float* Wr1   = (const float*)d_in[13];
    const float* br1   = (const float*)d_in[14];
    const float* att1  = (const float*)d_in[15];
    const float* bias1 = (const float*)d_in[16];
    const float* bn1_g = (const float*)d_in[17];
    const float* bn1_b = (const float*)d_in[18];
    const float* bn1_m = (const float*)d_in[19];
    const float* bn1_v = (const float*)d_in[20];
    const float* Wl2   = (const float*)d_in[21];
    const float* bl2   = (const float*)d_in[22];
    const float* Wr2   = (const float*)d_in[23];
    const float* br2   = (const float*)d_in[24];
    const float* att2  = (const float*)d_in[25];
    const float* bias2 = (const float*)d_in[26];
    const float* bn2_g = (const float*)d_in[27];
    const float* bn2_b = (const float*)d_in[28];
    const float* bn2_m = (const float*)d_in[29];
    const float* bn2_v = (const float*)d_in[30];
    const float* predW = (const float*)d_in[31];
    const float* predb = (const float*)d_in[32];

    float* ws = (float*)d_ws;
    __half* xh    = (__half*)ws;                       // N*96 halves  = 4.8M floats
    float*  p0    = ws + 4800000;
    __half* xcat1 = (__half*)p0;                       // N*256 halves = 12.8M floats
    float*  p1    = p0 + 12800000;
    __half* h1h   = (__half*)p1;                       // N*128 halves = 6.4M floats
    float*  p2    = p1 + 6400000;
    __half* xcat2 = (__half*)p2;                       // N*64 halves  = 3.2M floats
    float*  p3    = p2 + 3200000;
    __half* h2h   = (__half*)p3;                       // N*32 halves  = 1.6M floats
    float*  p4    = p3 + 1600000;
    __half* wcat1 = (__half*)p4;                       // 256*96 h = 12288 f
    float*  bcat1 = p4 + 12288;                        // 256
    __half* wcat2 = (__half*)(bcat1 + 256);            // 64*128 h = 4096 f
    float*  bcat2 = bcat1 + 256 + 4096;                // 64
    __half* wpred = (__half*)(bcat2 + 64);             // 64*32 h = 1024 f
    float*  bpred = bcat2 + 64 + 1024;                 // 64
    int*    ib    = (int*)(bpred + 64);
    unsigned* ebuf = (unsigned*)ib;                    // NEP
    int*    hist   = ib + NEP;                         // HISTN
    int*    part   = hist + HISTN;                     // 128
    int*    off    = part + 128;                       // NN+1
    int*    csr    = off + NN + 1;                     // NEP

    float* out = (float*)d_out;

    // ---- CSR build (deterministic radix partition, no global atomics) ----
    part_hist<<<NBLK, 256, 0, stream>>>(ei, hist);
    scan_p1<<<HSCAN_BLOCKS, 256, 0, stream>>>(hist, part, HISTN);
    scan_p2<<<1, 128, 0, stream>>>(part, HSCAN_BLOCKS, off);
    scan_p3<<<HSCAN_BLOCKS, 256, 0, stream>>>(hist, part, HISTN);
    part_scatter<<<NBLK, 256, 0, stream>>>(ei, hist, ebuf);
    bucket_csr<<<NBUCK2, 256, 0, stream>>>(hist, ebuf, off, csr);

    // ---- node features (fp16, self-padding) ----
    bio_kernel<<<(NN + 255) / 256, 256, 0, stream>>>(
        x_bio, bioW1, biob1, bn0_g, bn0_b, bn0_m, bn0_v, bioW2, biob2, xh);
    copy_pca<<<(NN * 50 + 255) / 256, 256, 0, stream>>>(x_pca, xh);

    // ---- weight conversion ----
    wconvert<<<96, 256, 0, stream>>>(Wl1, Wr1, bl1, br1, wcat1, bcat1, 128, 66, 96);
    wconvert<<<32, 256, 0, stream>>>(Wl2, Wr2, bl2, br2, wcat2, bcat2, 32, 128, 128);
    wpred_conv<<<8, 256, 0, stream>>>(predW, predb, wpred, bpred);

    // ---- layer-1 transform ----
    mfma_gemm<3, 256, false><<<(NN + 63) / 64, 256, 0, stream>>>(xh, wcat1, bcat1, xcat1, NN, 0);

    // ---- fused layer-1 edge phase ----
    fused_gat1<<<(NN + 3) / 4, 256, 0, stream>>>(
        off, csr, (const __half2*)xcat1, att1, bias1, bn1_g, bn1_b, bn1_m, bn1_v, (__half2*)h1h);

    // ---- layer-2 transform ----
    mfma_gemm<4, 64, false><<<(NN + 63) / 64, 256, 0, stream>>>(h1h, wcat2, bcat2, xcat2, NN, 0);

    // ---- fused layer-2 edge phase ----
    fused_gat2<<<(NN + 3) / 4, 256, 0, stream>>>(
        off, csr, (const __half2*)xcat2, att2, bias2, bn2_g, bn2_b, bn2_m, bn2_v, (__half2*)h2h);

    // ---- prediction head (MFMA, fp32 out) ----
    mfma_gemm<1, 64, true><<<(NN + 63) / 64, 256, 0, stream>>>(h2h, wpred, bpred, out, NN, 50);
}

// Round 8
// 432.251 us; speedup vs baseline: 2.3468x; 1.1147x over previous
//
#include <hip/hip_runtime.h>
#include <hip/hip_fp16.h>
#include <cstdint>
#include <cstddef>

#define NN 100000
#define NE 1600000
#define NEP (NE + NN)              // 1,700,000
#define NBLK 200                   // partition blocks
#define CHUNK ((NEP + NBLK - 1) / NBLK)   // 8500
#define NBUCK2 ((NN + 255) / 256)  // 391 buckets of 256 dst nodes
#define HISTN (NBUCK2 * NBLK)      // 78,200
#define HSCAN_BLOCKS ((HISTN + 1023) / 1024)  // 77

typedef __attribute__((ext_vector_type(8))) _Float16 half8;
typedef __attribute__((ext_vector_type(4))) _Float16 h4v;
typedef __attribute__((ext_vector_type(2))) _Float16 h2v;
typedef __attribute__((ext_vector_type(4))) float float4v;

__device__ __forceinline__ float elu_f(float x) {
    return x > 0.f ? x : __expf(x) - 1.f;
}

// ---- DPP reduce helpers (pure VALU) ----
template<int CTRL>
__device__ __forceinline__ float dpp_add(float x) {
    int s = __builtin_amdgcn_update_dpp(0, __float_as_int(x), CTRL, 0xF, 0xF, true);
    return x + __int_as_float(s);
}
// allsum within aligned 8-lane groups: quad xor1, quad xor2, row_half_mirror(xor7)
__device__ __forceinline__ float sum8_all(float x) {
    x = dpp_add<0xB1>(x); x = dpp_add<0x4E>(x); x = dpp_add<0x141>(x);
    return x;
}
// allsum within aligned 16-lane rows: + row_mirror
__device__ __forceinline__ float sum16_all(float x) {
    x = dpp_add<0xB1>(x); x = dpp_add<0x4E>(x); x = dpp_add<0x141>(x); x = dpp_add<0x140>(x);
    return x;
}

__device__ __forceinline__ float dot2f(h2v a, h2v b, float c) {
#if __has_builtin(__builtin_amdgcn_fdot2)
    return __builtin_amdgcn_fdot2(a, b, c, false);
#else
    return fmaf((float)a[0], (float)b[0], fmaf((float)a[1], (float)b[1], c));
#endif
}

__device__ __forceinline__ h2v hmax2v(h2v a, h2v b) {
#if __has_builtin(__builtin_elementwise_max)
    return __builtin_elementwise_max(a, b);
#else
    __half2 r = __hmax2(*(__half2*)&a, *(__half2*)&b);
    return *(h2v*)&r;
#endif
}

// ================= CSR build: deterministic radix partition =================

__global__ __launch_bounds__(256) void part_hist(const int* __restrict__ ei, int* __restrict__ hist)
{
    __shared__ int cnt[NBUCK2];
    int tid = threadIdx.x, k = blockIdx.x;
    for (int i = tid; i < NBUCK2; i += 256) cnt[i] = 0;
    __syncthreads();
    int e0 = k * CHUNK, e1 = min(e0 + CHUNK, NEP);
    for (int e = e0 + tid; e < e1; e += 256) {
        int dst = (e < NE) ? ei[NE + e] : e - NE;
        atomicAdd(&cnt[dst >> 8], 1);
    }
    __syncthreads();
    for (int i = tid; i < NBUCK2; i += 256) hist[i * NBLK + k] = cnt[i];
}

__global__ __launch_bounds__(256) void scan_p1(const int* __restrict__ src, int* __restrict__ part, int n)
{
    __shared__ int wsum[4];
    int t = threadIdx.x;
    int i0 = blockIdx.x * 1024 + t * 4;
    int s = 0;
    if (i0 + 3 < n) { int4 d = *(const int4*)(src + i0); s = d.x + d.y + d.z + d.w; }
    else { for (int k = 0; k < 4; k++) if (i0 + k < n) s += src[i0 + k]; }
    for (int d = 1; d < 64; d <<= 1) s += __shfl_xor(s, d, 64);
    if ((t & 63) == 0) wsum[t >> 6] = s;
    __syncthreads();
    if (t == 0) part[blockIdx.x] = wsum[0] + wsum[1] + wsum[2] + wsum[3];
}

__global__ __launch_bounds__(128) void scan_p2(int* __restrict__ part, int nb, int* __restrict__ off)
{
    __shared__ int wt[2];
    int t = threadIdx.x;
    int lane = t & 63, w = t >> 6;
    int v = (t < nb) ? part[t] : 0;
    int x = v;
    for (int d = 1; d < 64; d <<= 1) { int y = __shfl_up(x, d, 64); if (lane >= d) x += y; }
    if (lane == 63) wt[w] = x;
    __syncthreads();
    int base = (w == 1) ? wt[0] : 0;
    int excl = base + x - v;
    if (t < nb) part[t] = excl;
    if (t == 0) off[NN] = NEP;
}

__global__ __launch_bounds__(256) void scan_p3(int* __restrict__ data, const int* __restrict__ part, int n)
{
    __shared__ int wsum[4];
    int t = threadIdx.x, lane = t & 63, w = t >> 6;
    int i0 = blockIdx.x * 1024 + t * 4;
    int d0 = 0, d1 = 0, d2 = 0, d3 = 0;
    if (i0 + 3 < n) { int4 d = *(const int4*)(data + i0); d0 = d.x; d1 = d.y; d2 = d.z; d3 = d.w; }
    else if (i0 < n) {
        d0 = data[i0];
        if (i0 + 1 < n) d1 = data[i0 + 1];
        if (i0 + 2 < n) d2 = data[i0 + 2];
    }
    int s = d0 + d1 + d2 + d3;
    int x = s;
    for (int d = 1; d < 64; d <<= 1) { int y = __shfl_up(x, d, 64); if (lane >= d) x += y; }
    if (lane == 63) wsum[w] = x;
    __syncthreads();
    int wb = 0;
    for (int i = 0; i < w; i++) wb += wsum[i];
    int base = part[blockIdx.x] + wb + x - s;
    if (i0 < n)     data[i0]     = base;
    if (i0 + 1 < n) data[i0 + 1] = base + d0;
    if (i0 + 2 < n) data[i0 + 2] = base + d0 + d1;
    if (i0 + 3 < n) data[i0 + 3] = base + d0 + d1 + d2;
}

__global__ __launch_bounds__(256) void part_scatter(const int* __restrict__ ei,
                                                    const int* __restrict__ hist,
                                                    unsigned* __restrict__ ebuf)
{
    __shared__ int cur[NBUCK2];
    int tid = threadIdx.x, k = blockIdx.x;
    for (int i = tid; i < NBUCK2; i += 256) cur[i] = hist[i * NBLK + k];
    __syncthreads();
    int e0 = k * CHUNK, e1 = min(e0 + CHUNK, NEP);
    for (int e = e0 + tid; e < e1; e += 256) {
        int src, dst;
        if (e < NE) { src = ei[e]; dst = ei[NE + e]; } else { src = dst = e - NE; }
        int pos = atomicAdd(&cur[dst >> 8], 1);
        ebuf[pos] = (unsigned)src | ((unsigned)(dst & 255) << 24);
    }
}

__global__ __launch_bounds__(256) void bucket_csr(const int* __restrict__ hist,
                                                  const unsigned* __restrict__ ebuf,
                                                  int* __restrict__ off, int* __restrict__ csr)
{
    __shared__ int cnt[256];
    __shared__ int cur[256];
    __shared__ int wsum[4];
    int b = blockIdx.x;
    int d0 = b << 8;
    int tid = threadIdx.x;
    int e0 = hist[b * NBLK];
    int e1 = (b + 1 < NBUCK2) ? hist[(b + 1) * NBLK] : NEP;
    cnt[tid] = 0;
    __syncthreads();
    for (int i = e0 + tid; i < e1; i += 256) atomicAdd(&cnt[ebuf[i] >> 24], 1);
    __syncthreads();
    int c = cnt[tid];
    int x = c;
    int lane = tid & 63, w = tid >> 6;
    for (int d = 1; d < 64; d <<= 1) { int y = __shfl_up(x, d, 64); if (lane >= d) x += y; }
    if (lane == 63) wsum[w] = x;
    __syncthreads();
    int wb = 0;
    for (int i = 0; i < w; i++) wb += wsum[i];
    int excl = wb + x - c;
    cur[tid] = e0 + excl;
    int node = d0 + tid;
    if (node < NN) off[node] = e0 + excl;
    __syncthreads();
    for (int i = e0 + tid; i < e1; i += 256) {
        unsigned v = ebuf[i];
        int p = atomicAdd(&cur[v >> 24], 1);
        csr[p] = (int)(v & 0xFFFFFF);
    }
}

// ================= node feature prep (fp16 x [N][96]; bio + pca + pad fused) =================

__global__ __launch_bounds__(256) void bio_kernel(
    const float* __restrict__ xb, const float* __restrict__ xp,
    const float* __restrict__ W1, const float* __restrict__ b1,
    const float* __restrict__ g0, const float* __restrict__ bb0,
    const float* __restrict__ m0, const float* __restrict__ v0,
    const float* __restrict__ W2, const float* __restrict__ b2,
    __half* __restrict__ xh)
{
    __shared__ float sW1[16*64], sW2[16*16], sb1[16], sb2[16], ss[16], st[16];
    int tid = threadIdx.x;
    for (int idx = tid; idx < 1024; idx += 256) sW1[idx] = W1[idx];
    if (tid < 256) sW2[tid] = W2[tid];
    if (tid < 16) {
        sb1[tid] = b1[tid]; sb2[tid] = b2[tid];
        float s = g0[tid] * rsqrtf(v0[tid] + 1e-5f);
        ss[tid] = s; st[tid] = bb0[tid] - m0[tid] * s;
    }
    __syncthreads();
    int i = blockIdx.x * 256 + tid;
    if (i >= NN) return;
    float bio[64];
    const float4* p = (const float4*)(xb + (size_t)i * 64);
    #pragma unroll
    for (int q = 0; q < 16; q++) {
        float4 f = p[q];
        bio[q*4] = f.x; bio[q*4+1] = f.y; bio[q*4+2] = f.z; bio[q*4+3] = f.w;
    }
    float t1[16];
    #pragma unroll
    for (int j = 0; j < 16; j++) {
        float acc = sb1[j];
        #pragma unroll
        for (int k = 0; k < 64; k++) acc += bio[k] * sW1[j*64 + k];
        acc = acc * ss[j] + st[j];
        t1[j] = elu_f(acc);
    }
    __half* xrow = xh + (size_t)i * 96;
    // pca cols 0..49 (row base i*200 B is 8-B aligned)
    const float* xpr = xp + (size_t)i * 50;
    #pragma unroll
    for (int j = 0; j < 25; j++) {
        float2 f = *(const float2*)(xpr + 2 * j);
        *(__half2*)(xrow + 2 * j) = __floats2half2_rn(f.x, f.y);
    }
    // bio cols 50..65
    #pragma unroll
    for (int j = 0; j < 16; j++) {
        float acc = sb2[j];
        #pragma unroll
        for (int k = 0; k < 16; k++) acc += t1[k] * sW2[j*16 + k];
        xrow[50 + j] = __float2half(elu_f(acc));
    }
    // zero pad cols 66..95
    __half2 z2 = __floats2half2_rn(0.f, 0.f);
    #pragma unroll
    for (int j = 0; j < 15; j++) *(__half2*)(xrow + 66 + 2 * j) = z2;
}

// ================= all weight conversions in one launch =================

__global__ __launch_bounds__(256) void wconvert_all(
    const float* __restrict__ Wl1, const float* __restrict__ Wr1,
    const float* __restrict__ bl1, const float* __restrict__ br1,
    const float* __restrict__ Wl2, const float* __restrict__ Wr2,
    const float* __restrict__ bl2, const float* __restrict__ br2,
    const float* __restrict__ predW, const float* __restrict__ predb,
    __half* __restrict__ wcat1, float* __restrict__ bcat1,
    __half* __restrict__ wcat2, float* __restrict__ bcat2,
    __half* __restrict__ wpred, float* __restrict__ bpred)
{
    int t = blockIdx.x * 256 + threadIdx.x;
    if (t < 256 * 96) {  // wcat1: [256][96], K=66
        int j = t / 96, k = t - j * 96;
        float v = (k < 66) ? ((j < 128) ? Wl1[j * 66 + k] : Wr1[(j - 128) * 66 + k]) : 0.f;
        wcat1[t] = __float2half(v);
    }
    int u = t - 256 * 96;
    if (u >= 0 && u < 64 * 128) {  // wcat2: [64][128]
        int j = u >> 7, k = u & 127;
        float v = (j < 32) ? Wl2[j * 128 + k] : Wr2[(j - 32) * 128 + k];
        wcat2[u] = __float2half(v);
    }
    int w = u - 64 * 128;
    if (w >= 0 && w < 64 * 32) {  // wpred: [64][32], rows 50..63 zero
        int j = w >> 5;
        wpred[w] = __float2half(j < 50 ? predW[w] : 0.f);
    }
    int z = w - 64 * 32;
    if (z >= 0 && z < 256) bcat1[z] = (z < 128) ? bl1[z] : br1[z - 128];
    int z2 = z - 256;
    if (z2 >= 0 && z2 < 64) bcat2[z2] = (z2 < 32) ? bl2[z2] : br2[z2 - 32];
    int z3 = z2 - 64;
    if (z3 >= 0 && z3 < 64) bpred[z3] = (z3 < 50) ? predb[z3] : 0.f;
}

// ================= MFMA f16 GEMM =================
template<int KT, int NC, bool FOUT>
__global__ __launch_bounds__(256) void mfma_gemm(
    const __half* __restrict__ in, const __half* __restrict__ wcat,
    const float* __restrict__ bcat, void* __restrict__ outv, int n, int ncol)
{
    constexpr int K = KT * 32;
    constexpr int KP = K + 8;
    __shared__ __half sW[NC * KP];
    __shared__ __half sX[64 * KP];
    __shared__ float sB[NC];
    int tid = threadIdx.x;
    for (int idx = tid * 8; idx < NC * K; idx += 256 * 8) {
        int r = idx / K, c = idx - r * K;
        *(half8*)(&sW[r * KP + c]) = *(const half8*)(&wcat[r * K + c]);
    }
    for (int idx = tid; idx < NC; idx += 256) sB[idx] = bcat[idx];
    int row0 = blockIdx.x * 64;
    half8 hz = {0, 0, 0, 0, 0, 0, 0, 0};
    for (int idx = tid * 8; idx < 64 * K; idx += 256 * 8) {
        int r = idx / K, c = idx - r * K;
        int gr = row0 + r;
        half8 v = (gr < n) ? *(const half8*)(&in[(size_t)gr * K + c]) : hz;
        *(half8*)(&sX[r * KP + c]) = v;
    }
    __syncthreads();
    int w = tid >> 6, lane = tid & 63;
    int m = lane & 15, quad = lane >> 4;
    half8 a[KT];
    #pragma unroll
    for (int kt = 0; kt < KT; kt++)
        a[kt] = *(const half8*)(&sX[(w * 16 + m) * KP + kt * 32 + quad * 8]);
    #pragma unroll 1
    for (int nt = 0; nt < NC / 16; nt++) {
        float4v acc = {0.f, 0.f, 0.f, 0.f};
        #pragma unroll
        for (int kt = 0; kt < KT; kt++) {
            half8 bfrag = *(const half8*)(&sW[(nt * 16 + m) * KP + kt * 32 + quad * 8]);
            acc = __builtin_amdgcn_mfma_f32_16x16x32_f16(a[kt], bfrag, acc, 0, 0, 0);
        }
        int col = nt * 16 + m;
        float bias = sB[col];
        #pragma unroll
        for (int i = 0; i < 4; i++) {
            int r = row0 + w * 16 + quad * 4 + i;
            if (r < n) {
                if (FOUT) { if (col < ncol) ((float*)outv)[(size_t)r * ncol + col] = acc[i] + bias; }
                else ((__half*)outv)[(size_t)r * NC + col] = __float2half(acc[i] + bias);
            }
        }
    }
}

// ================= fused GATv2 layer 1: one wave per dst node, 2 edges/iter =================
// xcat [N][256] fp16 (xl cols 0..127, xr 128..255). lane = slot(>>5)*32 + l;
// lane handles 4 channels ch=4l of its slot's edge. Head = 8 lanes -> sum8_all.
__global__ __launch_bounds__(256) void fused_gat1(
    const int* __restrict__ off, const int* __restrict__ csr,
    const __half* __restrict__ xcat, const float* __restrict__ att,
    const float* __restrict__ bias, const float* __restrict__ g,
    const float* __restrict__ b, const float* __restrict__ m,
    const float* __restrict__ v, __half* __restrict__ h1)
{
    int wave = threadIdx.x >> 6;
    int lane = threadIdx.x & 63;
    int node = blockIdx.x * 4 + wave;
    if (node >= NN) return;
    int slot = lane >> 5;
    int l = lane & 31;
    int ch = l * 4;

    h4v xr4 = *(const h4v*)(xcat + (size_t)node * 256 + 128 + ch);
    h2v xr01 = {xr4[0], xr4[1]}, xr23 = {xr4[2], xr4[3]};
    float4 af = *(const float4*)(att + ch);
    h2v a01 = {(_Float16)af.x, (_Float16)af.y};
    h2v a23 = {(_Float16)af.z, (_Float16)af.w};
    const h2v c2 = {(_Float16)0.2f, (_Float16)0.2f};

    int k0 = off[node], k1 = off[node + 1];
    float acc0 = 0.f, acc1 = 0.f, acc2 = 0.f, acc3 = 0.f, denom = 0.f;

    for (int base = k0; base < k1; base += 64) {
        int nb = min(64, k1 - base);
        int mysrc = (lane < nb) ? csr[base + lane] : 0;
        int p0 = __builtin_amdgcn_readlane(mysrc, 0);
        int p1 = __builtin_amdgcn_readlane(mysrc, nb > 1 ? 1 : 0);
        int ssel = slot ? p1 : p0;
        h4v cur = *(const h4v*)(xcat + (size_t)(unsigned)ssel * 256 + ch);
        for (int t = 0; t < nb; t += 2) {
            int t2 = (t + 2 < nb) ? t + 2 : nb - 1;
            int t3 = (t + 3 < nb) ? t + 3 : nb - 1;
            int n0 = __builtin_amdgcn_readlane(mysrc, t2);
            int n1 = __builtin_amdgcn_readlane(mysrc, t3);
            int nsel = slot ? n1 : n0;
            h4v nxt = *(const h4v*)(xcat + (size_t)(unsigned)nsel * 256 + ch);

            h2v xl01 = {cur[0], cur[1]}, xl23 = {cur[2], cur[3]};
            h2v s01 = xl01 + xr01, s23 = xl23 + xr23;
            h2v ls01 = hmax2v(s01, s01 * c2);
            h2v ls23 = hmax2v(s23, s23 * c2);
            float pp = dot2f(ls01, a01, dot2f(ls23, a23, 0.f));
            pp = sum8_all(pp);                  // per-head 32-ch logit
            bool valid = (t + slot) < nb;
            float wgt = valid ? __expf(pp) : 0.f;
            denom += wgt;
            acc0 = fmaf((float)cur[0], wgt, acc0);
            acc1 = fmaf((float)cur[1], wgt, acc1);
            acc2 = fmaf((float)cur[2], wgt, acc2);
            acc3 = fmaf((float)cur[3], wgt, acc3);
            cur = nxt;
        }
    }
    acc0 += __shfl_xor(acc0, 32, 64);
    acc1 += __shfl_xor(acc1, 32, 64);
    acc2 += __shfl_xor(acc2, 32, 64);
    acc3 += __shfl_xor(acc3, 32, 64);
    denom += __shfl_xor(denom, 32, 64);
    if (slot == 0) {
        float inv = 1.f / (denom + 1e-16f);
        float4 gv = *(const float4*)(g + ch);
        float4 vv = *(const float4*)(v + ch);
        float4 bv = *(const float4*)(b + ch);
        float4 mv = *(const float4*)(m + ch);
        float4 biv = *(const float4*)(bias + ch);
        float s0 = gv.x * rsqrtf(vv.x + 1e-5f);
        float s1 = gv.y * rsqrtf(vv.y + 1e-5f);
        float s2 = gv.z * rsqrtf(vv.z + 1e-5f);
        float s3 = gv.w * rsqrtf(vv.w + 1e-5f);
        float o0 = elu_f((acc0 * inv + biv.x) * s0 + (bv.x - mv.x * s0));
        float o1 = elu_f((acc1 * inv + biv.y) * s1 + (bv.y - mv.y * s1));
        float o2 = elu_f((acc2 * inv + biv.z) * s2 + (bv.z - mv.z * s2));
        float o3 = elu_f((acc3 * inv + biv.w) * s3 + (bv.w - mv.w * s3));
        h4v o = {(_Float16)o0, (_Float16)o1, (_Float16)o2, (_Float16)o3};
        *(h4v*)(h1 + (size_t)node * 128 + ch) = o;
    }
}

// ================= fused GATv2 layer 2: 4 edges/iter x 16 lanes x 2ch (pk math) =================
__global__ __launch_bounds__(256) void fused_gat2(
    const int* __restrict__ off, const int* __restrict__ csr,
    const __half* __restrict__ xcat2, const float* __restrict__ att,
    const float* __restrict__ bias, const float* __restrict__ g,
    const float* __restrict__ b, const float* __restrict__ m,
    const float* __restrict__ v, __half* __restrict__ h2)
{
    int wave = threadIdx.x >> 6;
    int lane = threadIdx.x & 63;
    int node = blockIdx.x * 4 + wave;
    if (node >= NN) return;
    int row = lane >> 4;
    int cp  = lane & 15;
    int c   = cp * 2;

    h2v xr = *(const h2v*)(xcat2 + (size_t)node * 64 + 32 + c);
    float2 af = *(const float2*)(att + c);
    h2v ah = {(_Float16)af.x, (_Float16)af.y};
    const h2v c2 = {(_Float16)0.2f, (_Float16)0.2f};

    int k0 = off[node], k1 = off[node + 1];
    float accx = 0.f, accy = 0.f, denom = 0.f;

    for (int base = k0; base < k1; base += 64) {
        int nb = min(64, k1 - base);
        int mysrc = (lane < nb) ? csr[base + lane] : 0;
        for (int t = 0; t < nb; t += 4) {
            int i1 = min(t + 1, nb - 1), i2 = min(t + 2, nb - 1), i3 = min(t + 3, nb - 1);
            int s0 = __builtin_amdgcn_readlane(mysrc, t);
            int s1 = __builtin_amdgcn_readlane(mysrc, i1);
            int s2 = __builtin_amdgcn_readlane(mysrc, i2);
            int s3 = __builtin_amdgcn_readlane(mysrc, i3);
            int sa  = (row & 1) ? s1 : s0;
            int sb_ = (row & 1) ? s3 : s2;
            int ss  = (row & 2) ? sb_ : sa;
            h2v xl = *(const h2v*)(xcat2 + (size_t)(unsigned)ss * 64 + c);
            h2v s = xl + xr;
            h2v ls = hmax2v(s, s * c2);
            float pp = dot2f(ls, ah, 0.f);
            pp = sum16_all(pp);
            bool valid = (t + row) < nb;
            float wgt = valid ? __expf(pp) : 0.f;
            denom += wgt;
            accx = fmaf((float)xl[0], wgt, accx);
            accy = fmaf((float)xl[1], wgt, accy);
        }
    }
    accx  += __shfl_xor(accx, 16, 64);  accx  += __shfl_xor(accx, 32, 64);
    accy  += __shfl_xor(accy, 16, 64);  accy  += __shfl_xor(accy, 32, 64);
    denom += __shfl_xor(denom, 16, 64); denom += __shfl_xor(denom, 32, 64);
    if (row == 0) {
        float inv = 1.f / (denom + 1e-16f);
        float sC0 = g[c]     * rsqrtf(v[c]     + 1e-5f);
        float sC1 = g[c + 1] * rsqrtf(v[c + 1] + 1e-5f);
        float o0 = elu_f((accx * inv + bias[c])     * sC0 + (b[c]     - m[c]     * sC0));
        float o1 = elu_f((accy * inv + bias[c + 1]) * sC1 + (b[c + 1] - m[c + 1] * sC1));
        *(__half2*)(h2 + (size_t)node * 32 + c) = __floats2half2_rn(o0, o1);
    }
}

extern "C" void kernel_launch(void* const* d_in, const int* in_sizes, int n_in,
                              void* d_out, int out_size, void* d_ws, size_t ws_size,
                              hipStream_t stream)
{
    const float* x_pca = (const float*)d_in[0];
    const float* x_bio = (const float*)d_in[1];
    const int*   ei    = (const int*)d_in[2];
    const float* bioW1 = (const float*)d_in[3];
    const float* biob1 = (const float*)d_in[4];
    const float* bn0_g = (const float*)d_in[5];
    const float* bn0_b = (const float*)d_in[6];
    const float* bn0_m = (const float*)d_in[7];
    const float* bn0_v = (const float*)d_in[8];
    const float* bioW2 = (const float*)d_in[9];
    const float* biob2 = (const float*)d_in[10];
    const float* Wl1   = (const float*)d_in[11];
    const float* bl1   = (const float*)d_in[12];
    const float* Wr1   = (const float*)d_in[13];
    const float* br1   = (const float*)d_in[14];
    const float* att1  = (const float*)d_in[15];
    const float* bias1 = (const float*)d_in[16];
    const float* bn1_g = (const float*)d_in[17];
    const float* bn1_b = (const float*)d_in[18];
    const float* bn1_m = (const float*)d_in[19];
    const float* bn1_v = (const float*)d_in[20];
    const float* Wl2   = (const float*)d_in[21];
    const float* bl2   = (const float*)d_in[22];
    const float* Wr2   = (const float*)d_in[23];
    const float* br2   = (const float*)d_in[24];
    const float* att2  = (const float*)d_in[25];
    const float* bias2 = (const float*)d_in[26];
    const float* bn2_g = (const float*)d_in[27];
    const float* bn2_b = (const float*)d_in[28];
    const float* bn2_m = (const float*)d_in[29];
    const float* bn2_v = (const float*)d_in[30];
    const float* predW = (const float*)d_in[31];
    const float* predb = (const float*)d_in[32];

    float* ws = (float*)d_ws;
    __half* xh    = (__half*)ws;                       // N*96 halves  = 4.8M floats
    float*  p0    = ws + 4800000;
    __half* xcat1 = (__half*)p0;                       // N*256 halves = 12.8M floats
    float*  p1    = p0 + 12800000;
    __half* h1h   = (__half*)p1;                       // N*128 halves = 6.4M floats
    float*  p2    = p1 + 6400000;
    __half* xcat2 = (__half*)p2;                       // N*64 halves  = 3.2M floats
    float*  p3    = p2 + 3200000;
    __half* h2h   = (__half*)p3;                       // N*32 halves  = 1.6M floats
    float*  p4    = p3 + 1600000;
    __half* wcat1 = (__half*)p4;                       // 256*96 h = 12288 f
    float*  bcat1 = p4 + 12288;                        // 256
    __half* wcat2 = (__half*)(bcat1 + 256);            // 64*128 h = 4096 f
    float*  bcat2 = bcat1 + 256 + 4096;                // 64
    __half* wpred = (__half*)(bcat2 + 64);             // 64*32 h = 1024 f
    float*  bpred = bcat2 + 64 + 1024;                 // 64
    int*    ib    = (int*)(bpred + 64);
    unsigned* ebuf = (unsigned*)ib;                    // NEP
    int*    hist   = ib + NEP;                         // HISTN
    int*    part   = hist + HISTN;                     // 128
    int*    off    = part + 128;                       // NN+1
    int*    csr    = off + NN + 1;                     // NEP

    float* out = (float*)d_out;

    // ---- CSR build (deterministic radix partition) ----
    part_hist<<<NBLK, 256, 0, stream>>>(ei, hist);
    scan_p1<<<HSCAN_BLOCKS, 256, 0, stream>>>(hist, part, HISTN);
    scan_p2<<<1, 128, 0, stream>>>(part, HSCAN_BLOCKS, off);
    scan_p3<<<HSCAN_BLOCKS, 256, 0, stream>>>(hist, part, HISTN);
    part_scatter<<<NBLK, 256, 0, stream>>>(ei, hist, ebuf);
    bucket_csr<<<NBUCK2, 256, 0, stream>>>(hist, ebuf, off, csr);

    // ---- node features (fp16, pca+bio+pad fused) ----
    bio_kernel<<<(NN + 255) / 256, 256, 0, stream>>>(
        x_bio, x_pca, bioW1, biob1, bn0_g, bn0_b, bn0_m, bn0_v, bioW2, biob2, xh);

    // ---- all weight conversions ----
    wconvert_all<<<138, 256, 0, stream>>>(
        Wl1, Wr1, bl1, br1, Wl2, Wr2, bl2, br2, predW, predb,
        wcat1, bcat1, wcat2, bcat2, wpred, bpred);

    // ---- layer-1 transform ----
    mfma_gemm<3, 256, false><<<(NN + 63) / 64, 256, 0, stream>>>(xh, wcat1, bcat1, xcat1, NN, 0);

    // ---- fused layer-1 edge phase ----
    fused_gat1<<<(NN + 3) / 4, 256, 0, stream>>>(
        off, csr, xcat1, att1, bias1, bn1_g, bn1_b, bn1_m, bn1_v, h1h);

    // ---- layer-2 transform ----
    mfma_gemm<4, 64, false><<<(NN + 63) / 64, 256, 0, stream>>>(h1h, wcat2, bcat2, xcat2, NN, 0);

    // ---- fused layer-2 edge phase ----
    fused_gat2<<<(NN + 3) / 4, 256, 0, stream>>>(
        off, csr, xcat2, att2, bias2, bn2_g, bn2_b, bn2_m, bn2_v, h2h);

    // ---- prediction head (MFMA, fp32 out) ----
    mfma_gemm<1, 64, true><<<(NN + 63) / 64, 256, 0, stream>>>(h2h, wpred, bpred, out, NN, 50);
}

// Round 9
// 412.561 us; speedup vs baseline: 2.4588x; 1.0477x over previous
//
#include <hip/hip_runtime.h>
#include <hip/hip_fp16.h>
#include <cstdint>
#include <cstddef>

#define NN 100000
#define NE 1600000
#define NEP (NE + NN)              // 1,700,000
#define NBLK 200                   // partition blocks
#define CHUNK ((NEP + NBLK - 1) / NBLK)   // 8500
#define NBUCK2 ((NN + 255) / 256)  // 391 buckets of 256 dst nodes
#define HISTN (NBUCK2 * NBLK)      // 78,200
#define HSCAN_BLOCKS ((HISTN + 1023) / 1024)  // 77

typedef __attribute__((ext_vector_type(8))) _Float16 half8;
typedef __attribute__((ext_vector_type(4))) _Float16 h4v;
typedef __attribute__((ext_vector_type(2))) _Float16 h2v;
typedef __attribute__((ext_vector_type(4))) float float4v;

__device__ __forceinline__ float elu_f(float x) {
    return x > 0.f ? x : __expf(x) - 1.f;
}

// ---- DPP reduce helpers (pure VALU) ----
template<int CTRL>
__device__ __forceinline__ float dpp_add(float x) {
    int s = __builtin_amdgcn_update_dpp(0, __float_as_int(x), CTRL, 0xF, 0xF, true);
    return x + __int_as_float(s);
}
// allsum within aligned 4-lane quads (one GAT1 head = 4 lanes x 8ch)
__device__ __forceinline__ float sum4_all(float x) {
    x = dpp_add<0xB1>(x); x = dpp_add<0x4E>(x);
    return x;
}
// allsum within aligned 8-lane groups (one GAT2 edge = 8 lanes x 4ch)
__device__ __forceinline__ float sum8_all(float x) {
    x = dpp_add<0xB1>(x); x = dpp_add<0x4E>(x); x = dpp_add<0x141>(x);
    return x;
}

__device__ __forceinline__ float dot2f(h2v a, h2v b, float c) {
#if __has_builtin(__builtin_amdgcn_fdot2)
    return __builtin_amdgcn_fdot2(a, b, c, false);
#else
    return fmaf((float)a[0], (float)b[0], fmaf((float)a[1], (float)b[1], c));
#endif
}

__device__ __forceinline__ h2v hmax2v(h2v a, h2v b) {
#if __has_builtin(__builtin_elementwise_max)
    return __builtin_elementwise_max(a, b);
#else
    __half2 r = __hmax2(*(__half2*)&a, *(__half2*)&b);
    return *(h2v*)&r;
#endif
}

// ================= CSR build: deterministic radix partition =================

__global__ __launch_bounds__(256) void part_hist(const int* __restrict__ ei, int* __restrict__ hist)
{
    __shared__ int cnt[NBUCK2];
    int tid = threadIdx.x, k = blockIdx.x;
    for (int i = tid; i < NBUCK2; i += 256) cnt[i] = 0;
    __syncthreads();
    int e0 = k * CHUNK, e1 = min(e0 + CHUNK, NEP);
    for (int e = e0 + tid; e < e1; e += 256) {
        int dst = (e < NE) ? ei[NE + e] : e - NE;
        atomicAdd(&cnt[dst >> 8], 1);
    }
    __syncthreads();
    for (int i = tid; i < NBUCK2; i += 256) hist[i * NBLK + k] = cnt[i];
}

__global__ __launch_bounds__(256) void scan_p1(const int* __restrict__ src, int* __restrict__ part, int n)
{
    __shared__ int wsum[4];
    int t = threadIdx.x;
    int i0 = blockIdx.x * 1024 + t * 4;
    int s = 0;
    if (i0 + 3 < n) { int4 d = *(const int4*)(src + i0); s = d.x + d.y + d.z + d.w; }
    else { for (int k = 0; k < 4; k++) if (i0 + k < n) s += src[i0 + k]; }
    for (int d = 1; d < 64; d <<= 1) s += __shfl_xor(s, d, 64);
    if ((t & 63) == 0) wsum[t >> 6] = s;
    __syncthreads();
    if (t == 0) part[blockIdx.x] = wsum[0] + wsum[1] + wsum[2] + wsum[3];
}

__global__ __launch_bounds__(128) void scan_p2(int* __restrict__ part, int nb, int* __restrict__ off)
{
    __shared__ int wt[2];
    int t = threadIdx.x;
    int lane = t & 63, w = t >> 6;
    int v = (t < nb) ? part[t] : 0;
    int x = v;
    for (int d = 1; d < 64; d <<= 1) { int y = __shfl_up(x, d, 64); if (lane >= d) x += y; }
    if (lane == 63) wt[w] = x;
    __syncthreads();
    int base = (w == 1) ? wt[0] : 0;
    int excl = base + x - v;
    if (t < nb) part[t] = excl;
    if (t == 0) off[NN] = NEP;
}

__global__ __launch_bounds__(256) void scan_p3(int* __restrict__ data, const int* __restrict__ part, int n)
{
    __shared__ int wsum[4];
    int t = threadIdx.x, lane = t & 63, w = t >> 6;
    int i0 = blockIdx.x * 1024 + t * 4;
    int d0 = 0, d1 = 0, d2 = 0, d3 = 0;
    if (i0 + 3 < n) { int4 d = *(const int4*)(data + i0); d0 = d.x; d1 = d.y; d2 = d.z; d3 = d.w; }
    else if (i0 < n) {
        d0 = data[i0];
        if (i0 + 1 < n) d1 = data[i0 + 1];
        if (i0 + 2 < n) d2 = data[i0 + 2];
    }
    int s = d0 + d1 + d2 + d3;
    int x = s;
    for (int d = 1; d < 64; d <<= 1) { int y = __shfl_up(x, d, 64); if (lane >= d) x += y; }
    if (lane == 63) wsum[w] = x;
    __syncthreads();
    int wb = 0;
    for (int i = 0; i < w; i++) wb += wsum[i];
    int base = part[blockIdx.x] + wb + x - s;
    if (i0 < n)     data[i0]     = base;
    if (i0 + 1 < n) data[i0 + 1] = base + d0;
    if (i0 + 2 < n) data[i0 + 2] = base + d0 + d1;
    if (i0 + 3 < n) data[i0 + 3] = base + d0 + d1 + d2;
}

__global__ __launch_bounds__(256) void part_scatter(const int* __restrict__ ei,
                                                    const int* __restrict__ hist,
                                                    unsigned* __restrict__ ebuf)
{
    __shared__ int cur[NBUCK2];
    int tid = threadIdx.x, k = blockIdx.x;
    for (int i = tid; i < NBUCK2; i += 256) cur[i] = hist[i * NBLK + k];
    __syncthreads();
    int e0 = k * CHUNK, e1 = min(e0 + CHUNK, NEP);
    for (int e = e0 + tid; e < e1; e += 256) {
        int src, dst;
        if (e < NE) { src = ei[e]; dst = ei[NE + e]; } else { src = dst = e - NE; }
        int pos = atomicAdd(&cur[dst >> 8], 1);
        ebuf[pos] = (unsigned)src | ((unsigned)(dst & 255) << 24);
    }
}

__global__ __launch_bounds__(256) void bucket_csr(const int* __restrict__ hist,
                                                  const unsigned* __restrict__ ebuf,
                                                  int* __restrict__ off, int* __restrict__ csr)
{
    __shared__ int cnt[256];
    __shared__ int cur[256];
    __shared__ int wsum[4];
    int b = blockIdx.x;
    int d0 = b << 8;
    int tid = threadIdx.x;
    int e0 = hist[b * NBLK];
    int e1 = (b + 1 < NBUCK2) ? hist[(b + 1) * NBLK] : NEP;
    cnt[tid] = 0;
    __syncthreads();
    for (int i = e0 + tid; i < e1; i += 256) atomicAdd(&cnt[ebuf[i] >> 24], 1);
    __syncthreads();
    int c = cnt[tid];
    int x = c;
    int lane = tid & 63, w = tid >> 6;
    for (int d = 1; d < 64; d <<= 1) { int y = __shfl_up(x, d, 64); if (lane >= d) x += y; }
    if (lane == 63) wsum[w] = x;
    __syncthreads();
    int wb = 0;
    for (int i = 0; i < w; i++) wb += wsum[i];
    int excl = wb + x - c;
    cur[tid] = e0 + excl;
    int node = d0 + tid;
    if (node < NN) off[node] = e0 + excl;
    __syncthreads();
    for (int i = e0 + tid; i < e1; i += 256) {
        unsigned v = ebuf[i];
        int p = atomicAdd(&cur[v >> 24], 1);
        csr[p] = (int)(v & 0xFFFFFF);
    }
}

// ================= node feature prep (fp16 x [N][96]; bio + pca + pad fused) =================

__global__ __launch_bounds__(256) void bio_kernel(
    const float* __restrict__ xb, const float* __restrict__ xp,
    const float* __restrict__ W1, const float* __restrict__ b1,
    const float* __restrict__ g0, const float* __restrict__ bb0,
    const float* __restrict__ m0, const float* __restrict__ v0,
    const float* __restrict__ W2, const float* __restrict__ b2,
    __half* __restrict__ xh)
{
    __shared__ float sW1[16*64], sW2[16*16], sb1[16], sb2[16], ss[16], st[16];
    int tid = threadIdx.x;
    for (int idx = tid; idx < 1024; idx += 256) sW1[idx] = W1[idx];
    if (tid < 256) sW2[tid] = W2[tid];
    if (tid < 16) {
        sb1[tid] = b1[tid]; sb2[tid] = b2[tid];
        float s = g0[tid] * rsqrtf(v0[tid] + 1e-5f);
        ss[tid] = s; st[tid] = bb0[tid] - m0[tid] * s;
    }
    __syncthreads();
    int i = blockIdx.x * 256 + tid;
    if (i >= NN) return;
    float bio[64];
    const float4* p = (const float4*)(xb + (size_t)i * 64);
    #pragma unroll
    for (int q = 0; q < 16; q++) {
        float4 f = p[q];
        bio[q*4] = f.x; bio[q*4+1] = f.y; bio[q*4+2] = f.z; bio[q*4+3] = f.w;
    }
    float t1[16];
    #pragma unroll
    for (int j = 0; j < 16; j++) {
        float acc = sb1[j];
        #pragma unroll
        for (int k = 0; k < 64; k++) acc += bio[k] * sW1[j*64 + k];
        acc = acc * ss[j] + st[j];
        t1[j] = elu_f(acc);
    }
    __half* xrow = xh + (size_t)i * 96;
    const float* xpr = xp + (size_t)i * 50;
    #pragma unroll
    for (int j = 0; j < 25; j++) {
        float2 f = *(const float2*)(xpr + 2 * j);
        *(__half2*)(xrow + 2 * j) = __floats2half2_rn(f.x, f.y);
    }
    #pragma unroll
    for (int j = 0; j < 16; j++) {
        float acc = sb2[j];
        #pragma unroll
        for (int k = 0; k < 16; k++) acc += t1[k] * sW2[j*16 + k];
        xrow[50 + j] = __float2half(elu_f(acc));
    }
    __half2 z2 = __floats2half2_rn(0.f, 0.f);
    #pragma unroll
    for (int j = 0; j < 15; j++) *(__half2*)(xrow + 66 + 2 * j) = z2;
}

// ================= all weight conversions in one launch =================

__global__ __launch_bounds__(256) void wconvert_all(
    const float* __restrict__ Wl1, const float* __restrict__ Wr1,
    const float* __restrict__ bl1, const float* __restrict__ br1,
    const float* __restrict__ Wl2, const float* __restrict__ Wr2,
    const float* __restrict__ bl2, const float* __restrict__ br2,
    const float* __restrict__ predW, const float* __restrict__ predb,
    __half* __restrict__ wcat1, float* __restrict__ bcat1,
    __half* __restrict__ wcat2, float* __restrict__ bcat2,
    __half* __restrict__ wpred, float* __restrict__ bpred)
{
    int t = blockIdx.x * 256 + threadIdx.x;
    if (t < 256 * 96) {
        int j = t / 96, k = t - j * 96;
        float v = (k < 66) ? ((j < 128) ? Wl1[j * 66 + k] : Wr1[(j - 128) * 66 + k]) : 0.f;
        wcat1[t] = __float2half(v);
    }
    int u = t - 256 * 96;
    if (u >= 0 && u < 64 * 128) {
        int j = u >> 7, k = u & 127;
        float v = (j < 32) ? Wl2[j * 128 + k] : Wr2[(j - 32) * 128 + k];
        wcat2[u] = __float2half(v);
    }
    int w = u - 64 * 128;
    if (w >= 0 && w < 64 * 32) {
        int j = w >> 5;
        wpred[w] = __float2half(j < 50 ? predW[w] : 0.f);
    }
    int z = w - 64 * 32;
    if (z >= 0 && z < 256) bcat1[z] = (z < 128) ? bl1[z] : br1[z - 128];
    int z2 = z - 256;
    if (z2 >= 0 && z2 < 64) bcat2[z2] = (z2 < 32) ? bl2[z2] : br2[z2 - 32];
    int z3 = z2 - 64;
    if (z3 >= 0 && z3 < 64) bpred[z3] = (z3 < 50) ? predb[z3] : 0.f;
}

// ================= MFMA f16 GEMM =================
template<int KT, int NC, bool FOUT>
__global__ __launch_bounds__(256) void mfma_gemm(
    const __half* __restrict__ in, const __half* __restrict__ wcat,
    const float* __restrict__ bcat, void* __restrict__ outv, int n, int ncol)
{
    constexpr int K = KT * 32;
    constexpr int KP = K + 8;
    __shared__ __half sW[NC * KP];
    __shared__ __half sX[64 * KP];
    __shared__ float sB[NC];
    int tid = threadIdx.x;
    for (int idx = tid * 8; idx < NC * K; idx += 256 * 8) {
        int r = idx / K, c = idx - r * K;
        *(half8*)(&sW[r * KP + c]) = *(const half8*)(&wcat[r * K + c]);
    }
    for (int idx = tid; idx < NC; idx += 256) sB[idx] = bcat[idx];
    int row0 = blockIdx.x * 64;
    half8 hz = {0, 0, 0, 0, 0, 0, 0, 0};
    for (int idx = tid * 8; idx < 64 * K; idx += 256 * 8) {
        int r = idx / K, c = idx - r * K;
        int gr = row0 + r;
        half8 v = (gr < n) ? *(const half8*)(&in[(size_t)gr * K + c]) : hz;
        *(half8*)(&sX[r * KP + c]) = v;
    }
    __syncthreads();
    int w = tid >> 6, lane = tid & 63;
    int m = lane & 15, quad = lane >> 4;
    half8 a[KT];
    #pragma unroll
    for (int kt = 0; kt < KT; kt++)
        a[kt] = *(const half8*)(&sX[(w * 16 + m) * KP + kt * 32 + quad * 8]);
    #pragma unroll 1
    for (int nt = 0; nt < NC / 16; nt++) {
        float4v acc = {0.f, 0.f, 0.f, 0.f};
        #pragma unroll
        for (int kt = 0; kt < KT; kt++) {
            half8 bfrag = *(const half8*)(&sW[(nt * 16 + m) * KP + kt * 32 + quad * 8]);
            acc = __builtin_amdgcn_mfma_f32_16x16x32_f16(a[kt], bfrag, acc, 0, 0, 0);
        }
        int col = nt * 16 + m;
        float bias = sB[col];
        #pragma unroll
        for (int i = 0; i < 4; i++) {
            int r = row0 + w * 16 + quad * 4 + i;
            if (r < n) {
                if (FOUT) { if (col < ncol) ((float*)outv)[(size_t)r * ncol + col] = acc[i] + bias; }
                else ((__half*)outv)[(size_t)r * NC + col] = __float2half(acc[i] + bias);
            }
        }
    }
}

// ================= fused GATv2 layer 1: 4 edges/iter x 16 lanes x 8ch =================
// xcat [N][256] fp16 (xl cols 0..127, xr 128..255). row=lane>>4 = edge slot,
// cl=lane&15, ch=8*cl. Head = 32 ch = 4 lanes = one aligned quad -> sum4_all.
__global__ __launch_bounds__(256) void fused_gat1(
    const int* __restrict__ off, const int* __restrict__ csr,
    const __half* __restrict__ xcat, const float* __restrict__ att,
    const float* __restrict__ bias, const float* __restrict__ g,
    const float* __restrict__ b, const float* __restrict__ m,
    const float* __restrict__ v, __half* __restrict__ h1)
{
    int wave = threadIdx.x >> 6;
    int lane = threadIdx.x & 63;
    int node = blockIdx.x * 4 + wave;
    if (node >= NN) return;
    int row = lane >> 4;       // edge slot 0..3
    int cl  = lane & 15;
    int ch  = cl * 8;

    half8 xr8 = *(const half8*)(xcat + (size_t)node * 256 + 128 + ch);
    float4 af0 = *(const float4*)(att + ch);
    float4 af1 = *(const float4*)(att + ch + 4);
    h2v a01 = {(_Float16)af0.x, (_Float16)af0.y};
    h2v a23 = {(_Float16)af0.z, (_Float16)af0.w};
    h2v a45 = {(_Float16)af1.x, (_Float16)af1.y};
    h2v a67 = {(_Float16)af1.z, (_Float16)af1.w};
    h2v xr01 = {xr8[0], xr8[1]}, xr23 = {xr8[2], xr8[3]};
    h2v xr45 = {xr8[4], xr8[5]}, xr67 = {xr8[6], xr8[7]};
    const h2v c2 = {(_Float16)0.2f, (_Float16)0.2f};

    int k0 = off[node], k1 = off[node + 1];
    float acc0 = 0.f, acc1 = 0.f, acc2 = 0.f, acc3 = 0.f;
    float acc4 = 0.f, acc5 = 0.f, acc6 = 0.f, acc7 = 0.f, denom = 0.f;

    for (int base = k0; base < k1; base += 64) {
        int nb = min(64, k1 - base);
        int mysrc = (lane < nb) ? csr[base + lane] : 0;
        int nbm1 = nb - 1;
        int ss = __shfl(mysrc, min(row, nbm1), 64);
        half8 cur = *(const half8*)(xcat + (size_t)(unsigned)ss * 256 + ch);
        for (int t = 0; t < nb; t += 4) {
            int ns = __shfl(mysrc, min(t + 4 + row, nbm1), 64);
            half8 nxt = *(const half8*)(xcat + (size_t)(unsigned)ns * 256 + ch);

            h2v xl01 = {cur[0], cur[1]}, xl23 = {cur[2], cur[3]};
            h2v xl45 = {cur[4], cur[5]}, xl67 = {cur[6], cur[7]};
            h2v s01 = xl01 + xr01, s23 = xl23 + xr23;
            h2v s45 = xl45 + xr45, s67 = xl67 + xr67;
            h2v l01 = hmax2v(s01, s01 * c2);
            h2v l23 = hmax2v(s23, s23 * c2);
            h2v l45 = hmax2v(s45, s45 * c2);
            h2v l67 = hmax2v(s67, s67 * c2);
            float pp = dot2f(l01, a01, dot2f(l23, a23, dot2f(l45, a45, dot2f(l67, a67, 0.f))));
            pp = sum4_all(pp);                 // per-head (quad) logit
            bool valid = (t + row) < nb;
            float wgt = valid ? __expf(pp) : 0.f;
            denom += wgt;
            acc0 = fmaf((float)cur[0], wgt, acc0);
            acc1 = fmaf((float)cur[1], wgt, acc1);
            acc2 = fmaf((float)cur[2], wgt, acc2);
            acc3 = fmaf((float)cur[3], wgt, acc3);
            acc4 = fmaf((float)cur[4], wgt, acc4);
            acc5 = fmaf((float)cur[5], wgt, acc5);
            acc6 = fmaf((float)cur[6], wgt, acc6);
            acc7 = fmaf((float)cur[7], wgt, acc7);
            cur = nxt;
        }
    }
    // combine the 4 edge slots
    acc0 += __shfl_xor(acc0, 16, 64); acc0 += __shfl_xor(acc0, 32, 64);
    acc1 += __shfl_xor(acc1, 16, 64); acc1 += __shfl_xor(acc1, 32, 64);
    acc2 += __shfl_xor(acc2, 16, 64); acc2 += __shfl_xor(acc2, 32, 64);
    acc3 += __shfl_xor(acc3, 16, 64); acc3 += __shfl_xor(acc3, 32, 64);
    acc4 += __shfl_xor(acc4, 16, 64); acc4 += __shfl_xor(acc4, 32, 64);
    acc5 += __shfl_xor(acc5, 16, 64); acc5 += __shfl_xor(acc5, 32, 64);
    acc6 += __shfl_xor(acc6, 16, 64); acc6 += __shfl_xor(acc6, 32, 64);
    acc7 += __shfl_xor(acc7, 16, 64); acc7 += __shfl_xor(acc7, 32, 64);
    denom += __shfl_xor(denom, 16, 64); denom += __shfl_xor(denom, 32, 64);
    if (row == 0) {
        float inv = 1.f / (denom + 1e-16f);
        float4 g0v = *(const float4*)(g + ch),    g1v = *(const float4*)(g + ch + 4);
        float4 v0v = *(const float4*)(v + ch),    v1v = *(const float4*)(v + ch + 4);
        float4 b0v = *(const float4*)(b + ch),    b1v = *(const float4*)(b + ch + 4);
        float4 m0v = *(const float4*)(m + ch),    m1v = *(const float4*)(m + ch + 4);
        float4 i0v = *(const float4*)(bias + ch), i1v = *(const float4*)(bias + ch + 4);
        float sc, o[8];
        sc = g0v.x * rsqrtf(v0v.x + 1e-5f); o[0] = elu_f((acc0 * inv + i0v.x) * sc + (b0v.x - m0v.x * sc));
        sc = g0v.y * rsqrtf(v0v.y + 1e-5f); o[1] = elu_f((acc1 * inv + i0v.y) * sc + (b0v.y - m0v.y * sc));
        sc = g0v.z * rsqrtf(v0v.z + 1e-5f); o[2] = elu_f((acc2 * inv + i0v.z) * sc + (b0v.z - m0v.z * sc));
        sc = g0v.w * rsqrtf(v0v.w + 1e-5f); o[3] = elu_f((acc3 * inv + i0v.w) * sc + (b0v.w - m0v.w * sc));
        sc = g1v.x * rsqrtf(v1v.x + 1e-5f); o[4] = elu_f((acc4 * inv + i1v.x) * sc + (b1v.x - m1v.x * sc));
        sc = g1v.y * rsqrtf(v1v.y + 1e-5f); o[5] = elu_f((acc5 * inv + i1v.y) * sc + (b1v.y - m1v.y * sc));
        sc = g1v.z * rsqrtf(v1v.z + 1e-5f); o[6] = elu_f((acc6 * inv + i1v.z) * sc + (b1v.z - m1v.z * sc));
        sc = g1v.w * rsqrtf(v1v.w + 1e-5f); o[7] = elu_f((acc7 * inv + i1v.w) * sc + (b1v.w - m1v.w * sc));
        half8 oh = {(_Float16)o[0], (_Float16)o[1], (_Float16)o[2], (_Float16)o[3],
                    (_Float16)o[4], (_Float16)o[5], (_Float16)o[6], (_Float16)o[7]};
        *(half8*)(h1 + (size_t)node * 128 + ch) = oh;
    }
}

// ================= fused GATv2 layer 2: 8 edges/iter x 8 lanes x 4ch =================
// xcat2 [N][64] fp16 (xl 0..31, xr 32..63). row=lane>>3 = edge slot, cl=lane&7, ch=4*cl.
__global__ __launch_bounds__(256) void fused_gat2(
    const int* __restrict__ off, const int* __restrict__ csr,
    const __half* __restrict__ xcat2, const float* __restrict__ att,
    const float* __restrict__ bias, const float* __restrict__ g,
    const float* __restrict__ b, const float* __restrict__ m,
    const float* __restrict__ v, __half* __restrict__ h2)
{
    int wave = threadIdx.x >> 6;
    int lane = threadIdx.x & 63;
    int node = blockIdx.x * 4 + wave;
    if (node >= NN) return;
    int row = lane >> 3;       // edge slot 0..7
    int cl  = lane & 7;
    int ch  = cl * 4;

    h4v xr4 = *(const h4v*)(xcat2 + (size_t)node * 64 + 32 + ch);
    h2v xr01 = {xr4[0], xr4[1]}, xr23 = {xr4[2], xr4[3]};
    float4 af = *(const float4*)(att + ch);
    h2v a01 = {(_Float16)af.x, (_Float16)af.y};
    h2v a23 = {(_Float16)af.z, (_Float16)af.w};
    const h2v c2 = {(_Float16)0.2f, (_Float16)0.2f};

    int k0 = off[node], k1 = off[node + 1];
    float acc0 = 0.f, acc1 = 0.f, acc2 = 0.f, acc3 = 0.f, denom = 0.f;

    for (int base = k0; base < k1; base += 64) {
        int nb = min(64, k1 - base);
        int mysrc = (lane < nb) ? csr[base + lane] : 0;
        int nbm1 = nb - 1;
        int ss = __shfl(mysrc, min(row, nbm1), 64);
        h4v cur = *(const h4v*)(xcat2 + (size_t)(unsigned)ss * 64 + ch);
        for (int t = 0; t < nb; t += 8) {
            int ns = __shfl(mysrc, min(t + 8 + row, nbm1), 64);
            h4v nxt = *(const h4v*)(xcat2 + (size_t)(unsigned)ns * 64 + ch);

            h2v xl01 = {cur[0], cur[1]}, xl23 = {cur[2], cur[3]};
            h2v s01 = xl01 + xr01, s23 = xl23 + xr23;
            h2v l01 = hmax2v(s01, s01 * c2);
            h2v l23 = hmax2v(s23, s23 * c2);
            float pp = dot2f(l01, a01, dot2f(l23, a23, 0.f));
            pp = sum8_all(pp);                 // per-edge 32-ch logit
            bool valid = (t + row) < nb;
            float wgt = valid ? __expf(pp) : 0.f;
            denom += wgt;
            acc0 = fmaf((float)cur[0], wgt, acc0);
            acc1 = fmaf((float)cur[1], wgt, acc1);
            acc2 = fmaf((float)cur[2], wgt, acc2);
            acc3 = fmaf((float)cur[3], wgt, acc3);
            cur = nxt;
        }
    }
    // combine the 8 edge slots
    acc0 += __shfl_xor(acc0, 8, 64); acc0 += __shfl_xor(acc0, 16, 64); acc0 += __shfl_xor(acc0, 32, 64);
    acc1 += __shfl_xor(acc1, 8, 64); acc1 += __shfl_xor(acc1, 16, 64); acc1 += __shfl_xor(acc1, 32, 64);
    acc2 += __shfl_xor(acc2, 8, 64); acc2 += __shfl_xor(acc2, 16, 64); acc2 += __shfl_xor(acc2, 32, 64);
    acc3 += __shfl_xor(acc3, 8, 64); acc3 += __shfl_xor(acc3, 16, 64); acc3 += __shfl_xor(acc3, 32, 64);
    denom += __shfl_xor(denom, 8, 64); denom += __shfl_xor(denom, 16, 64); denom += __shfl_xor(denom, 32, 64);
    if (row == 0) {
        float inv = 1.f / (denom + 1e-16f);
        float4 gv = *(const float4*)(g + ch);
        float4 vv = *(const float4*)(v + ch);
        float4 bv = *(const float4*)(b + ch);
        float4 mv = *(const float4*)(m + ch);
        float4 iv = *(const float4*)(bias + ch);
        float sc, o0, o1, o2, o3;
        sc = gv.x * rsqrtf(vv.x + 1e-5f); o0 = elu_f((acc0 * inv + iv.x) * sc + (bv.x - mv.x * sc));
        sc = gv.y * rsqrtf(vv.y + 1e-5f); o1 = elu_f((acc1 * inv + iv.y) * sc + (bv.y - mv.y * sc));
        sc = gv.z * rsqrtf(vv.z + 1e-5f); o2 = elu_f((acc2 * inv + iv.z) * sc + (bv.z - mv.z * sc));
        sc = gv.w * rsqrtf(vv.w + 1e-5f); o3 = elu_f((acc3 * inv + iv.w) * sc + (bv.w - mv.w * sc));
        h4v oh = {(_Float16)o0, (_Float16)o1, (_Float16)o2, (_Float16)o3};
        *(h4v*)(h2 + (size_t)node * 32 + ch) = oh;
    }
}

extern "C" void kernel_launch(void* const* d_in, const int* in_sizes, int n_in,
                              void* d_out, int out_size, void* d_ws, size_t ws_size,
                              hipStream_t stream)
{
    const float* x_pca = (const float*)d_in[0];
    const float* x_bio = (const float*)d_in[1];
    const int*   ei    = (const int*)d_in[2];
    const float* bioW1 = (const float*)d_in[3];
    const float* biob1 = (const float*)d_in[4];
    const float* bn0_g = (const float*)d_in[5];
    const float* bn0_b = (const float*)d_in[6];
    const float* bn0_m = (const float*)d_in[7];
    const float* bn0_v = (const float*)d_in[8];
    const float* bioW2 = (const float*)d_in[9];
    const float* biob2 = (const float*)d_in[10];
    const float* Wl1   = (const float*)d_in[11];
    const float* bl1   = (const float*)d_in[12];
    const float* Wr1   = (const float*)d_in[13];
    const float* br1   = (const float*)d_in[14];
    const float* att1  = (const float*)d_in[15];
    const float* bias1 = (const float*)d_in[16];
    const float* bn1_g = (const float*)d_in[17];
    const float* bn1_b = (const float*)d_in[18];
    const float* bn1_m = (const float*)d_in[19];
    const float* bn1_v = (const float*)d_in[20];
    const float* Wl2   = (const float*)d_in[21];
    const float* bl2   = (const float*)d_in[22];
    const float* Wr2   = (const float*)d_in[23];
    const float* br2   = (const float*)d_in[24];
    const float* att2  = (const float*)d_in[25];
    const float* bias2 = (const float*)d_in[26];
    const float* bn2_g = (const float*)d_in[27];
    const float* bn2_b = (const float*)d_in[28];
    const float* bn2_m = (const float*)d_in[29];
    const float* bn2_v = (const float*)d_in[30];
    const float* predW = (const float*)d_in[31];
    const float* predb = (const float*)d_in[32];

    float* ws = (float*)d_ws;
    __half* xh    = (__half*)ws;                       // N*96 halves
    float*  p0    = ws + 4800000;
    __half* xcat1 = (__half*)p0;                       // N*256 halves
    float*  p1    = p0 + 12800000;
    __half* h1h   = (__half*)p1;                       // N*128 halves
    float*  p2    = p1 + 6400000;
    __half* xcat2 = (__half*)p2;                       // N*64 halves
    float*  p3    = p2 + 3200000;
    __half* h2h   = (__half*)p3;                       // N*32 halves
    float*  p4    = p3 + 1600000;
    __half* wcat1 = (__half*)p4;                       // 256*96 h
    float*  bcat1 = p4 + 12288;                        // 256
    __half* wcat2 = (__half*)(bcat1 + 256);            // 64*128 h
    float*  bcat2 = bcat1 + 256 + 4096;                // 64
    __half* wpred = (__half*)(bcat2 + 64);             // 64*32 h
    float*  bpred = bcat2 + 64 + 1024;                 // 64
    int*    ib    = (int*)(bpred + 64);
    unsigned* ebuf = (unsigned*)ib;                    // NEP
    int*    hist   = ib + NEP;                         // HISTN
    int*    part   = hist + HISTN;                     // 128
    int*    off    = part + 128;                       // NN+1
    int*    csr    = off + NN + 1;                     // NEP

    float* out = (float*)d_out;

    // ---- CSR build (deterministic radix partition) ----
    part_hist<<<NBLK, 256, 0, stream>>>(ei, hist);
    scan_p1<<<HSCAN_BLOCKS, 256, 0, stream>>>(hist, part, HISTN);
    scan_p2<<<1, 128, 0, stream>>>(part, HSCAN_BLOCKS, off);
    scan_p3<<<HSCAN_BLOCKS, 256, 0, stream>>>(hist, part, HISTN);
    part_scatter<<<NBLK, 256, 0, stream>>>(ei, hist, ebuf);
    bucket_csr<<<NBUCK2, 256, 0, stream>>>(hist, ebuf, off, csr);

    // ---- node features (fp16, pca+bio+pad fused) ----
    bio_kernel<<<(NN + 255) / 256, 256, 0, stream>>>(
        x_bio, x_pca, bioW1, biob1, bn0_g, bn0_b, bn0_m, bn0_v, bioW2, biob2, xh);

    // ---- all weight conversions ----
    wconvert_all<<<138, 256, 0, stream>>>(
        Wl1, Wr1, bl1, br1, Wl2, Wr2, bl2, br2, predW, predb,
        wcat1, bcat1, wcat2, bcat2, wpred, bpred);

    // ---- layer-1 transform ----
    mfma_gemm<3, 256, false><<<(NN + 63) / 64, 256, 0, stream>>>(xh, wcat1, bcat1, xcat1, NN, 0);

    // ---- fused layer-1 edge phase ----
    fused_gat1<<<(NN + 3) / 4, 256, 0, stream>>>(
        off, csr, xcat1, att1, bias1, bn1_g, bn1_b, bn1_m, bn1_v, h1h);

    // ---- layer-2 transform ----
    mfma_gemm<4, 64, false><<<(NN + 63) / 64, 256, 0, stream>>>(h1h, wcat2, bcat2, xcat2, NN, 0);

    // ---- fused layer-2 edge phase ----
    fused_gat2<<<(NN + 3) / 4, 256, 0, stream>>>(
        off, csr, xcat2, att2, bias2, bn2_g, bn2_b, bn2_m, bn2_v, h2h);

    // ---- prediction head (MFMA, fp32 out) ----
    mfma_gemm<1, 64, true><<<(NN + 63) / 64, 256, 0, stream>>>(h2h, wpred, bpred, out, NN, 50);
}